// Round 8
// baseline (416.742 us; speedup 1.0000x reference)
//
#include <hip/hip_runtime.h>
#include <stdint.h>

typedef __bf16 bf16;
typedef __bf16 bf16x8 __attribute__((ext_vector_type(8)));  // 16B
typedef __bf16 bf16x4 __attribute__((ext_vector_type(4)));  // 8B
typedef float  f32x4  __attribute__((ext_vector_type(4)));

#define MFMA_BF16(a, b, c) __builtin_amdgcn_mfma_f32_16x16x32_bf16((a), (b), (c), 0, 0, 0)

static constexpr int BATCH = 2;
static constexpr int SEQ   = 2048;
static constexpr int DIM   = 1024;
static constexpr int HDIM  = 64;
static constexpr int MROWS = BATCH * SEQ;   // 4096

typedef const __attribute__((address_space(1))) void* gvp;
typedef __attribute__((address_space(3))) void* svp;
__device__ __forceinline__ void glds16(const bf16* g, bf16* l) {
    __builtin_amdgcn_global_load_lds((gvp)(const void*)g, (svp)(void*)l, 16, 0, 0);
}

// scan leading nscan u16 of buffer as bf16; any exponent>=0x89 (|x|>=1024 /
// inf / nan) -> fp32 data misread as bf16 (P~0.46 per elem; deterministic
// across blocks since all scan identical bytes). True bf16 here has |x|<6.
__device__ __forceinline__ int scan_f32(const void* p, int nscan, int t) {
    const unsigned short* s = (const unsigned short*)p;
    int local = 0;
    for (int j = t; j < nscan; j += 256)
        local |= (((s[j] >> 7) & 0xFF) >= 0x89) ? 1 : 0;
    return local;
}

__device__ __forceinline__ bf16x8 cvt8(const float4 a, const float4 b) {
    bf16x8 r = {(bf16)a.x, (bf16)a.y, (bf16)a.z, (bf16)a.w,
                (bf16)b.x, (bf16)b.y, (bf16)b.z, (bf16)b.w};
    return r;
}

__device__ __forceinline__ bf16x8 cvt8v(const f32x4 a, const f32x4 b) {
    bf16x8 r = {(bf16)a[0], (bf16)a[1], (bf16)a[2], (bf16)a[3],
                (bf16)b[0], (bf16)b[1], (bf16)b[2], (bf16)b[3]};
    return r;
}

// ---------------------------------------------------------------------------
// Convert pass (R7 structure): dtype-adaptive fp32|bf16 -> bf16 workspace
// copies. 2052 blocks, 16 KB/block in 4 rounds.
// ---------------------------------------------------------------------------
__global__ __launch_bounds__(256) void convert_kernel(
    const void* __restrict__ q,  const void* __restrict__ k,  const void* __restrict__ v,
    const void* __restrict__ wq, const void* __restrict__ wk, const void* __restrict__ wv,
    const void* __restrict__ wo,
    const void* __restrict__ b_q, const void* __restrict__ b_k,
    const void* __restrict__ b_v, const void* __restrict__ b_o,
    bf16* __restrict__ qd,  bf16* __restrict__ kd,  bf16* __restrict__ vd,
    bf16* __restrict__ wqd, bf16* __restrict__ wkd, bf16* __restrict__ wvd,
    bf16* __restrict__ wod,
    bf16* __restrict__ bqd, bf16* __restrict__ bkd,
    bf16* __restrict__ bvd, bf16* __restrict__ bod,
    int* __restrict__ flagsOut)
{
    const int bid = blockIdx.x;
    int id, chunk;
    if (bid < 1536)      { id = bid >> 9;                chunk = bid & 511; }
    else if (bid < 2048) { id = 3 + ((bid - 1536) >> 7); chunk = (bid - 1536) & 127; }
    else                 { id = 7 + (bid - 2048);        chunk = 0; }

    const void* src; bf16* dst; int nelem, nscan;
    switch (id) {
        case 0:  src = q;   dst = qd;  nelem = 1 << 22; nscan = 4096; break;
        case 1:  src = k;   dst = kd;  nelem = 1 << 22; nscan = 4096; break;
        case 2:  src = v;   dst = vd;  nelem = 1 << 22; nscan = 4096; break;
        case 3:  src = wq;  dst = wqd; nelem = 1 << 20; nscan = 4096; break;
        case 4:  src = wk;  dst = wkd; nelem = 1 << 20; nscan = 4096; break;
        case 5:  src = wv;  dst = wvd; nelem = 1 << 20; nscan = 4096; break;
        case 6:  src = wo;  dst = wod; nelem = 1 << 20; nscan = 4096; break;
        case 7:  src = b_q; dst = bqd; nelem = 1024;    nscan = 1024; break;
        case 8:  src = b_k; dst = bkd; nelem = 1024;    nscan = 1024; break;
        case 9:  src = b_v; dst = bvd; nelem = 1024;    nscan = 1024; break;
        default: src = b_o; dst = bod; nelem = 1024;    nscan = 1024; break;
    }

    __shared__ int sbad;
    const int t = threadIdx.x;
    if (t == 0) sbad = 0;
    __syncthreads();
    int loc = scan_f32(src, nscan, t);
    if (loc) atomicOr(&sbad, 1);
    __syncthreads();
    const bool f32 = sbad != 0;

    if (id == 0 && chunk == 0 && t == 0) flagsOut[0] = f32 ? 1 : 0;

    if (id < 7) {
        const int base0 = chunk * 8192 + t * 8;
        if (f32) {
            const float* s = (const float*)src;
#pragma unroll
            for (int r = 0; r < 4; ++r) {
                const int base = base0 + r * 2048;
                const float4 a  = *(const float4*)(s + base);
                const float4 b2 = *(const float4*)(s + base + 4);
                *(bf16x8*)(dst + base) = cvt8(a, b2);
            }
        } else {
            const bf16* s = (const bf16*)src;
#pragma unroll
            for (int r = 0; r < 4; ++r) {
                const int base = base0 + r * 2048;
                *(bf16x8*)(dst + base) = *(const bf16x8*)(s + base);
            }
        }
    } else {
        const int base = t * 8;
        if (base < nelem) {
            if (f32) {
                const float* s = (const float*)src + base;
                const float4 a  = *(const float4*)s;
                const float4 b2 = *(const float4*)(s + 4);
                *(bf16x8*)(dst + base) = cvt8(a, b2);
            } else {
                *(bf16x8*)(dst + base) = *(const bf16x8*)((const bf16*)src + base);
            }
        }
    }
}

// ---------------------------------------------------------------------------
// QKV GEMM, all-bf16 (m97 structure): C = A @ W^T + bias. Both operands
// staged via glds16. 128x128 tile, BK=32, 2-barrier K-loop. z==2 (V) stores
// C transposed per head: Vt_g[b][h][e][s], vectorized bf16x4 along s.
// ---------------------------------------------------------------------------
__global__ __launch_bounds__(256, 3) void gemm_qkv_kernel(
    const bf16* __restrict__ A0, const bf16* __restrict__ W0,
    const bf16* __restrict__ b0, bf16* __restrict__ C0,
    const bf16* __restrict__ A1, const bf16* __restrict__ W1,
    const bf16* __restrict__ b1, bf16* __restrict__ C1,
    const bf16* __restrict__ A2, const bf16* __restrict__ W2,
    const bf16* __restrict__ b2, bf16* __restrict__ Vtg)
{
    const int z = blockIdx.z;
    const bf16* A  = (z == 0) ? A0 : (z == 1) ? A1 : A2;
    const bf16* W  = (z == 0) ? W0 : (z == 1) ? W1 : W2;
    const bf16* bi = (z == 0) ? b0 : (z == 1) ? b1 : b2;

    __shared__ bf16 As[128 * 32];
    __shared__ bf16 Bs[128 * 32];

    const int t = threadIdx.x;
    const int n0 = blockIdx.x * 128;
    const int m0 = blockIdx.y * 128;
    const int w    = t >> 6;
    const int lane = t & 63;
    const int ln   = t & 15;
    const int quad = (t >> 4) & 3;
    const int wm   = (w & 1) * 64;
    const int wn   = (w >> 1) * 64;

    const int srow = w * 32 + (lane >> 2);
    const int scol = (lane & 3) * 8;
    const bf16* gA = A + (size_t)(m0 + srow) * DIM + scol;
    const bf16* gW = W + (size_t)(n0 + srow) * DIM + scol;
    bf16* lA = &As[w * 32 * 32];
    bf16* lW = &Bs[w * 32 * 32];

    f32x4 acc[4][4];
#pragma unroll
    for (int i = 0; i < 4; ++i)
#pragma unroll
        for (int j = 0; j < 4; ++j) acc[i][j] = (f32x4){0.f, 0.f, 0.f, 0.f};

    for (int k0 = 0; k0 < DIM; k0 += 32) {
        __syncthreads();
        glds16(gA + k0,            lA);
        glds16(gA + 16 * DIM + k0, lA + 16 * 32);
        glds16(gW + k0,            lW);
        glds16(gW + 16 * DIM + k0, lW + 16 * 32);
        __syncthreads();

        bf16x8 af[4], bfr[4];
#pragma unroll
        for (int mt = 0; mt < 4; ++mt)
            af[mt] = *(const bf16x8*)&As[(wm + mt * 16 + ln) * 32 + quad * 8];
#pragma unroll
        for (int nt = 0; nt < 4; ++nt)
            bfr[nt] = *(const bf16x8*)&Bs[(wn + nt * 16 + ln) * 32 + quad * 8];
#pragma unroll
        for (int mt = 0; mt < 4; ++mt)
#pragma unroll
            for (int nt = 0; nt < 4; ++nt)
                acc[mt][nt] = MFMA_BF16(af[mt], bfr[nt], acc[mt][nt]);
    }

    if (z == 2) {
        // V epilogue: store transposed per head -> Vt_g[((b*16+h)*64+e)*SEQ + s]
#pragma unroll
        for (int nt = 0; nt < 4; ++nt) {
            const int col = n0 + wn + nt * 16 + ln;       // d
            const int h2 = col >> 6, e = col & 63;
            const float bv = (float)bi[col];
#pragma unroll
            for (int mt = 0; mt < 4; ++mt) {
                const int row = m0 + wm + mt * 16 + quad * 4;
                const int bb = row >> 11, s = row & 2047;
                bf16x4 o = {(bf16)(acc[mt][nt][0] + bv), (bf16)(acc[mt][nt][1] + bv),
                            (bf16)(acc[mt][nt][2] + bv), (bf16)(acc[mt][nt][3] + bv)};
                *(bf16x4*)&Vtg[((size_t)((bb * 16 + h2) * 64 + e)) * SEQ + s] = o;
            }
        }
    } else {
        bf16* C = (z == 0) ? C0 : C1;
#pragma unroll
        for (int nt = 0; nt < 4; ++nt) {
            const int col = n0 + wn + nt * 16 + ln;
            const float bv = (float)bi[col];
#pragma unroll
            for (int mt = 0; mt < 4; ++mt)
#pragma unroll
                for (int r = 0; r < 4; ++r) {
                    const int row = m0 + wm + mt * 16 + quad * 4 + r;
                    C[(size_t)row * DIM + col] = (bf16)(acc[mt][nt][r] + bv);
                }
        }
    }
}

// ---------------------------------------------------------------------------
// Output GEMM (R7 structure): 64x128 tile -> 512 blocks = 2/CU. C = A@Wo^T+bo.
// ---------------------------------------------------------------------------
__global__ __launch_bounds__(256, 4) void gemm_out_kernel(
    const bf16* __restrict__ A, const bf16* __restrict__ W,
    const bf16* __restrict__ bi, void* __restrict__ C,
    const int* __restrict__ flags)
{
    __shared__ bf16 As[64 * 32];
    __shared__ bf16 Bs[128 * 32];

    const int t = threadIdx.x;
    const bool of32 = flags[0] != 0;

    const int n0 = blockIdx.x * 128;
    const int m0 = blockIdx.y * 64;
    const int w    = t >> 6;
    const int lane = t & 63;
    const int ln   = t & 15;
    const int quad = (t >> 4) & 3;
    const int wm   = (w & 1) * 32;
    const int wn   = (w >> 1) * 64;

    const int arow = w * 16 + (lane >> 2);
    const int wrow = w * 32 + (lane >> 2);
    const int scol = (lane & 3) * 8;
    const bf16* gA = A + (size_t)(m0 + arow) * DIM + scol;
    const bf16* gW = W + (size_t)(n0 + wrow) * DIM + scol;
    bf16* lA = &As[(w * 16) * 32];
    bf16* lW = &Bs[(w * 32) * 32];

    f32x4 acc[2][4];
#pragma unroll
    for (int i = 0; i < 2; ++i)
#pragma unroll
        for (int j = 0; j < 4; ++j) acc[i][j] = (f32x4){0.f, 0.f, 0.f, 0.f};

    for (int k0 = 0; k0 < DIM; k0 += 32) {
        __syncthreads();
        glds16(gA + k0,            lA);
        glds16(gW + k0,            lW);
        glds16(gW + 16 * DIM + k0, lW + 16 * 32);
        __syncthreads();

        bf16x8 af[2], bfr[4];
#pragma unroll
        for (int mt = 0; mt < 2; ++mt)
            af[mt] = *(const bf16x8*)&As[(wm + mt * 16 + ln) * 32 + quad * 8];
#pragma unroll
        for (int nt = 0; nt < 4; ++nt)
            bfr[nt] = *(const bf16x8*)&Bs[(wn + nt * 16 + ln) * 32 + quad * 8];
#pragma unroll
        for (int mt = 0; mt < 2; ++mt)
#pragma unroll
            for (int nt = 0; nt < 4; ++nt)
                acc[mt][nt] = MFMA_BF16(af[mt], bfr[nt], acc[mt][nt]);
    }

#pragma unroll
    for (int nt = 0; nt < 4; ++nt) {
        const int col = n0 + wn + nt * 16 + ln;
        const float bv = (float)bi[col];
#pragma unroll
        for (int mt = 0; mt < 2; ++mt)
#pragma unroll
            for (int r = 0; r < 4; ++r) {
                const int row = m0 + wm + mt * 16 + quad * 4 + r;
                if (of32) ((float*)C)[(size_t)row * DIM + col] = acc[mt][nt][r] + bv;
                else      ((bf16*)C)[(size_t)row * DIM + col] = (bf16)(acc[mt][nt][r] + bv);
            }
    }
}

// ---------------------------------------------------------------------------
// Flash attention: R5's in-register-P structure (pi K-row permutation ->
// QK^T output layout == PV A-operand layout; zero cross-lane P traffic,
// zero P-LDS) at 4 BLOCKS/CU: single-buffered K/V (dbuf proven null in R4),
// LDS = 16+16 = 32 KB, launch_bounds(256,4) -> 4 waves/SIMD, 2x the TLP of
// all previous attn variants with UNCHANGED per-block compute:staging ratio.
// Inter-block TLP hides the staging drain + softmax serial chains (m97
// mechanism). Defer-max THR=0 (exact). Source-side XOR-chunk swizzles:
//   Ks[rho][e]: phys chunk c holds logical chunk c^(rho&7); row rho holds
//               global K row pi(rho) = (nt&3)*32 + quad*8 + (nt>>2)*4 + r
//   Vt[e][k]:   phys chunk c holds logical chunk c^(e&15)
// ---------------------------------------------------------------------------
__global__ __launch_bounds__(256, 4) void attn_kernel(
    const bf16* __restrict__ Q, const bf16* __restrict__ K,
    const bf16* __restrict__ Vtg, bf16* __restrict__ O)
{
    const int qt = blockIdx.x;        // 0..15: 128 q-rows
    const int bh = blockIdx.y;        // 0..31
    const int b  = bh >> 4;
    const int h  = bh & 15;

    __shared__ bf16 Ks[128 * 64];     // pi-row-permuted + chunk-swizzled (16 KB)
    __shared__ bf16 Vt[64 * 128];     // chunk-swizzled, stride 128 (16 KB)

    const int t    = threadIdx.x;
    const int w    = t >> 6;
    const int lane = t & 63;
    const int ln   = lane & 15;
    const int quad = lane >> 4;

    const int q0 = qt * 128;

    const float sc = 0.125f * 1.44269504089f;   // 1/sqrt(HD) * log2(e)
    bf16x8 qf[2][2];
#pragma unroll
    for (int g = 0; g < 2; ++g) {
        const bf16* qrow = Q + (size_t)(b * SEQ + q0 + w * 32 + g * 16 + ln) * DIM + h * HDIM;
        qf[g][0] = *(const bf16x8*)(qrow + quad * 8);
        qf[g][1] = *(const bf16x8*)(qrow + 32 + quad * 8);
#pragma unroll
        for (int i = 0; i < 8; ++i) {
            qf[g][0][i] = (bf16)((float)qf[g][0][i] * sc);
            qf[g][1][i] = (bf16)((float)qf[g][1][i] * sc);
        }
    }

    f32x4 o_acc[2][4];
#pragma unroll
    for (int g = 0; g < 2; ++g)
#pragma unroll
        for (int c = 0; c < 4; ++c) o_acc[g][c] = (f32x4){0.f, 0.f, 0.f, 0.f};
    float m_s[2] = {-1e30f, -1e30f};
    float l_s[2] = {0.f, 0.f};

    // K staging: wave w, instr i stages LDS rows w*32+i*8 .. +7; the GLOBAL
    // row for LDS row rho is pi(rho) (per-lane source address).
    const int kr_off = lane >> 3;               // row-in-group 0..7
    const int k_lc   = (lane & 7) ^ kr_off;     // logical chunk (source swizzle)
    // V staging: wave w, instr i stages e-rows w*16+i*4 .. +3 (4 rows x 16 chunks)
    const int ve_off = lane >> 4;               // 0..3
    const int v_pc   = lane & 15;               // phys chunk
    const size_t vrowbase = (size_t)((b * 16 + h) * 64);

    for (int kb = 0; kb < SEQ; kb += 128) {
        __syncthreads();              // prev-iter Ks/Vt reads complete
#pragma unroll
        for (int i = 0; i < 4; ++i) {
            const int nt_ = w * 2 + (i >> 1);
            const int qd_ = (i * 2 + (kr_off >> 2)) & 3;
            const int pr_ = (nt_ & 3) * 32 + qd_ * 8 + (nt_ >> 2) * 4 + (kr_off & 3);
            glds16(K + (size_t)(b * SEQ + kb + pr_) * DIM + h * HDIM + k_lc * 8,
                   &Ks[(w * 32 + i * 8) * 64]);
        }
#pragma unroll
        for (int i = 0; i < 4; ++i) {
            const int e2 = w * 16 + i * 4 + ve_off;
            const int lc = v_pc ^ (i * 4 + ve_off);
            glds16(Vtg + (vrowbase + e2) * SEQ + kb + lc * 8,
                   &Vt[(w * 16 + i * 4) * 128]);
        }
        __syncthreads();              // drains vmcnt: tiles visible

        // ---- S^T = K.Q^T for both q-groups; K-frags loaded once.
        // sa[nt][r] = S[q][k = (nt&3)*32 + quad*8 + (nt>>2)*4 + r]  (pi)
        f32x4 sa0[8], sa1[8];
#pragma unroll
        for (int nt = 0; nt < 8; ++nt) {
            const int rr = (nt * 16 + ln) * 64;
            const bf16x8 kf0 = *(const bf16x8*)&Ks[rr + ((quad ^ (ln & 7)) << 3)];
            const bf16x8 kf1 = *(const bf16x8*)&Ks[rr + (((quad + 4) ^ (ln & 7)) << 3)];
            f32x4 z0 = (f32x4){0.f, 0.f, 0.f, 0.f};
            z0 = MFMA_BF16(kf0, qf[0][0], z0);
            z0 = MFMA_BF16(kf1, qf[0][1], z0);
            sa0[nt] = z0;
            f32x4 z1 = (f32x4){0.f, 0.f, 0.f, 0.f};
            z1 = MFMA_BF16(kf0, qf[1][0], z1);
            z1 = MFMA_BF16(kf1, qf[1][1], z1);
            sa1[nt] = z1;
        }

        // ---- V frags (swizzled), loaded once for both groups
        bf16x8 vf[4][4];
#pragma unroll
        for (int kc = 0; kc < 4; ++kc)
#pragma unroll
            for (int c = 0; c < 4; ++c) {
                const int e = c * 16 + ln;
                const int pc = (kc * 4 + quad) ^ ln;
                vf[kc][c] = *(const bf16x8*)&Vt[e * 128 + pc * 8];
            }

        // ---- online softmax + in-register P repack + PV, per group
#pragma unroll
        for (int g = 0; g < 2; ++g) {
            f32x4* sa = g ? sa1 : sa0;
            float m8[8];
#pragma unroll
            for (int nt = 0; nt < 8; ++nt)
                m8[nt] = fmaxf(fmaxf(sa[nt][0], sa[nt][1]), fmaxf(sa[nt][2], sa[nt][3]));
            float mx = fmaxf(fmaxf(fmaxf(m8[0], m8[1]), fmaxf(m8[2], m8[3])),
                             fmaxf(fmaxf(m8[4], m8[5]), fmaxf(m8[6], m8[7])));
            mx = fmaxf(mx, __shfl_xor(mx, 16));
            mx = fmaxf(mx, __shfl_xor(mx, 32));
            // defer-max, THR=0: exact skip when the running max didn't grow
            if (!__all(mx <= m_s[g])) {
                const float mn = fmaxf(m_s[g], mx);
                const float al = exp2f(m_s[g] - mn);
                m_s[g] = mn;
                l_s[g] *= al;
#pragma unroll
                for (int r = 0; r < 4; ++r) {
                    const float alr = __shfl(al, quad * 4 + r);
#pragma unroll
                    for (int c = 0; c < 4; ++c) o_acc[g][c][r] *= alr;
                }
            }
            const float mn = m_s[g];
            float r8[8];
#pragma unroll
            for (int nt = 0; nt < 8; ++nt) {
                float p0 = exp2f(sa[nt][0] - mn);
                float p1 = exp2f(sa[nt][1] - mn);
                float p2 = exp2f(sa[nt][2] - mn);
                float p3 = exp2f(sa[nt][3] - mn);
                sa[nt][0] = p0; sa[nt][1] = p1; sa[nt][2] = p2; sa[nt][3] = p3;
                r8[nt] = (p0 + p1) + (p2 + p3);
            }
            float rs = ((r8[0] + r8[1]) + (r8[2] + r8[3])) +
                       ((r8[4] + r8[5]) + (r8[6] + r8[7]));
            rs += __shfl_xor(rs, 16);
            rs += __shfl_xor(rs, 32);
            l_s[g] += rs;

            // in-lane repack: pa[kc][j] = P[q][kc*32 + quad*8 + j]
            bf16x8 pa[4];
#pragma unroll
            for (int kc = 0; kc < 4; ++kc)
                pa[kc] = cvt8v(sa[kc], sa[kc + 4]);
#pragma unroll
            for (int kc = 0; kc < 4; ++kc)
#pragma unroll
                for (int c = 0; c < 4; ++c)
                    o_acc[g][c] = MFMA_BF16(pa[kc], vf[kc][c], o_acc[g][c]);
        }
    }

    // ---- epilogue: normalize, store bf16
#pragma unroll
    for (int g = 0; g < 2; ++g) {
        const float linv = 1.0f / l_s[g];
#pragma unroll
        for (int r = 0; r < 4; ++r) {
            const float lr = __shfl(linv, quad * 4 + r);
            const size_t rowoff =
                (size_t)(b * SEQ + q0 + w * 32 + g * 16 + quad * 4 + r) * DIM + h * HDIM;
#pragma unroll
            for (int c = 0; c < 4; ++c)
                O[rowoff + c * 16 + ln] = (bf16)(o_acc[g][c][r] * lr);
        }
    }
}

extern "C" void kernel_launch(void* const* d_in, const int* in_sizes, int n_in,
                              void* d_out, int out_size, void* d_ws, size_t ws_size,
                              hipStream_t stream) {
    // ws layout (bf16 elems): Qb,Kb,Vtg (4.19M each), qc,kc,vc (4.19M each;
    // qc is re-used as Ob after gemm_qkv has consumed it), Wq..Wo (1.05M
    // each), biases (1K each), flags. Total ~59 MB.
    const size_t NM = (size_t)MROWS * DIM;     // 4194304
    const size_t NW = (size_t)DIM * DIM;       // 1048576
    bf16* Qb  = (bf16*)d_ws;
    bf16* Kb  = Qb + NM;
    bf16* Vtg = Kb + NM;
    bf16* qc  = Vtg + NM;
    bf16* kc  = qc + NM;
    bf16* vc  = kc + NM;
    bf16* Wqc = vc + NM;
    bf16* Wkc = Wqc + NW;
    bf16* Wvc = Wkc + NW;
    bf16* Woc = Wvc + NW;
    bf16* bqc = Woc + NW;
    bf16* bkc = bqc + 1024;
    bf16* bvc = bkc + 1024;
    bf16* boc = bvc + 1024;
    int*  flags = (int*)(boc + 1024);
    bf16* Ob  = qc;   // alias: qc dead after gemm_qkv, Ob written by attn

    convert_kernel<<<dim3(2052), 256, 0, stream>>>(
        d_in[0], d_in[1], d_in[2],
        d_in[3], d_in[5], d_in[7], d_in[9],
        d_in[4], d_in[6], d_in[8], d_in[10],
        qc, kc, vc, Wqc, Wkc, Wvc, Woc, bqc, bkc, bvc, boc, flags);

    gemm_qkv_kernel<<<dim3(DIM / 128, MROWS / 128, 3), 256, 0, stream>>>(
        qc, Wqc, bqc, Qb,
        kc, Wkc, bkc, Kb,
        vc, Wvc, bvc, Vtg);

    attn_kernel<<<dim3(SEQ / 128, BATCH * 16), 256, 0, stream>>>(Qb, Kb, Vtg, Ob);

    gemm_out_kernel<<<dim3(DIM / 128, MROWS / 64), 256, 0, stream>>>(
        Ob, Woc, boc, d_out, flags);
}

// Round 9
// 295.776 us; speedup vs baseline: 1.4090x; 1.4090x over previous
//
#include <hip/hip_runtime.h>
#include <stdint.h>

typedef __bf16 bf16;
typedef __bf16 bf16x8 __attribute__((ext_vector_type(8)));  // 16B
typedef __bf16 bf16x4 __attribute__((ext_vector_type(4)));  // 8B
typedef float  f32x4  __attribute__((ext_vector_type(4)));

#define MFMA_BF16(a, b, c) __builtin_amdgcn_mfma_f32_16x16x32_bf16((a), (b), (c), 0, 0, 0)

static constexpr int BATCH = 2;
static constexpr int SEQ   = 2048;
static constexpr int DIM   = 1024;
static constexpr int HDIM  = 64;
static constexpr int MROWS = BATCH * SEQ;   // 4096

typedef const __attribute__((address_space(1))) void* gvp;
typedef __attribute__((address_space(3))) void* svp;
__device__ __forceinline__ void glds16(const bf16* g, bf16* l) {
    __builtin_amdgcn_global_load_lds((gvp)(const void*)g, (svp)(void*)l, 16, 0, 0);
}

// scan leading nscan u16 of buffer as bf16; any exponent>=0x89 (|x|>=1024 /
// inf / nan) -> fp32 data misread as bf16 (P~0.46 per elem; deterministic
// across blocks since all scan identical bytes). True bf16 here has |x|<6.
__device__ __forceinline__ int scan_f32(const void* p, int nscan, int t) {
    const unsigned short* s = (const unsigned short*)p;
    int local = 0;
    for (int j = t; j < nscan; j += 256)
        local |= (((s[j] >> 7) & 0xFF) >= 0x89) ? 1 : 0;
    return local;
}

__device__ __forceinline__ bf16x8 cvt8(const float4 a, const float4 b) {
    bf16x8 r = {(bf16)a.x, (bf16)a.y, (bf16)a.z, (bf16)a.w,
                (bf16)b.x, (bf16)b.y, (bf16)b.z, (bf16)b.w};
    return r;
}

// ---------------------------------------------------------------------------
// Convert pass (R7 structure): dtype-adaptive fp32|bf16 -> bf16 workspace
// copies. 2052 blocks, 16 KB/block in 4 rounds.
// ---------------------------------------------------------------------------
__global__ __launch_bounds__(256) void convert_kernel(
    const void* __restrict__ q,  const void* __restrict__ k,  const void* __restrict__ v,
    const void* __restrict__ wq, const void* __restrict__ wk, const void* __restrict__ wv,
    const void* __restrict__ wo,
    const void* __restrict__ b_q, const void* __restrict__ b_k,
    const void* __restrict__ b_v, const void* __restrict__ b_o,
    bf16* __restrict__ qd,  bf16* __restrict__ kd,  bf16* __restrict__ vd,
    bf16* __restrict__ wqd, bf16* __restrict__ wkd, bf16* __restrict__ wvd,
    bf16* __restrict__ wod,
    bf16* __restrict__ bqd, bf16* __restrict__ bkd,
    bf16* __restrict__ bvd, bf16* __restrict__ bod,
    int* __restrict__ flagsOut)
{
    const int bid = blockIdx.x;
    int id, chunk;
    if (bid < 1536)      { id = bid >> 9;                chunk = bid & 511; }
    else if (bid < 2048) { id = 3 + ((bid - 1536) >> 7); chunk = (bid - 1536) & 127; }
    else                 { id = 7 + (bid - 2048);        chunk = 0; }

    const void* src; bf16* dst; int nelem, nscan;
    switch (id) {
        case 0:  src = q;   dst = qd;  nelem = 1 << 22; nscan = 4096; break;
        case 1:  src = k;   dst = kd;  nelem = 1 << 22; nscan = 4096; break;
        case 2:  src = v;   dst = vd;  nelem = 1 << 22; nscan = 4096; break;
        case 3:  src = wq;  dst = wqd; nelem = 1 << 20; nscan = 4096; break;
        case 4:  src = wk;  dst = wkd; nelem = 1 << 20; nscan = 4096; break;
        case 5:  src = wv;  dst = wvd; nelem = 1 << 20; nscan = 4096; break;
        case 6:  src = wo;  dst = wod; nelem = 1 << 20; nscan = 4096; break;
        case 7:  src = b_q; dst = bqd; nelem = 1024;    nscan = 1024; break;
        case 8:  src = b_k; dst = bkd; nelem = 1024;    nscan = 1024; break;
        case 9:  src = b_v; dst = bvd; nelem = 1024;    nscan = 1024; break;
        default: src = b_o; dst = bod; nelem = 1024;    nscan = 1024; break;
    }

    __shared__ int sbad;
    const int t = threadIdx.x;
    if (t == 0) sbad = 0;
    __syncthreads();
    int loc = scan_f32(src, nscan, t);
    if (loc) atomicOr(&sbad, 1);
    __syncthreads();
    const bool f32 = sbad != 0;

    if (id == 0 && chunk == 0 && t == 0) flagsOut[0] = f32 ? 1 : 0;

    if (id < 7) {
        const int base0 = chunk * 8192 + t * 8;
        if (f32) {
            const float* s = (const float*)src;
#pragma unroll
            for (int r = 0; r < 4; ++r) {
                const int base = base0 + r * 2048;
                const float4 a  = *(const float4*)(s + base);
                const float4 b2 = *(const float4*)(s + base + 4);
                *(bf16x8*)(dst + base) = cvt8(a, b2);
            }
        } else {
            const bf16* s = (const bf16*)src;
#pragma unroll
            for (int r = 0; r < 4; ++r) {
                const int base = base0 + r * 2048;
                *(bf16x8*)(dst + base) = *(const bf16x8*)(s + base);
            }
        }
    } else {
        const int base = t * 8;
        if (base < nelem) {
            if (f32) {
                const float* s = (const float*)src + base;
                const float4 a  = *(const float4*)s;
                const float4 b2 = *(const float4*)(s + 4);
                *(bf16x8*)(dst + base) = cvt8(a, b2);
            } else {
                *(bf16x8*)(dst + base) = *(const bf16x8*)((const bf16*)src + base);
            }
        }
    }
}

// ---------------------------------------------------------------------------
// QKV GEMM, all-bf16 (m97 structure): C = A @ W^T + bias. Both operands
// staged via glds16. 128x128 tile, BK=32, 2-barrier K-loop. z==2 (V) stores
// C transposed per head: Vt_g[b][h][e][s], vectorized bf16x4 along s.
// ---------------------------------------------------------------------------
__global__ __launch_bounds__(256, 3) void gemm_qkv_kernel(
    const bf16* __restrict__ A0, const bf16* __restrict__ W0,
    const bf16* __restrict__ b0, bf16* __restrict__ C0,
    const bf16* __restrict__ A1, const bf16* __restrict__ W1,
    const bf16* __restrict__ b1, bf16* __restrict__ C1,
    const bf16* __restrict__ A2, const bf16* __restrict__ W2,
    const bf16* __restrict__ b2, bf16* __restrict__ Vtg)
{
    const int z = blockIdx.z;
    const bf16* A  = (z == 0) ? A0 : (z == 1) ? A1 : A2;
    const bf16* W  = (z == 0) ? W0 : (z == 1) ? W1 : W2;
    const bf16* bi = (z == 0) ? b0 : (z == 1) ? b1 : b2;

    __shared__ bf16 As[128 * 32];
    __shared__ bf16 Bs[128 * 32];

    const int t = threadIdx.x;
    const int n0 = blockIdx.x * 128;
    const int m0 = blockIdx.y * 128;
    const int w    = t >> 6;
    const int lane = t & 63;
    const int ln   = t & 15;
    const int quad = (t >> 4) & 3;
    const int wm   = (w & 1) * 64;
    const int wn   = (w >> 1) * 64;

    const int srow = w * 32 + (lane >> 2);
    const int scol = (lane & 3) * 8;
    const bf16* gA = A + (size_t)(m0 + srow) * DIM + scol;
    const bf16* gW = W + (size_t)(n0 + srow) * DIM + scol;
    bf16* lA = &As[w * 32 * 32];
    bf16* lW = &Bs[w * 32 * 32];

    f32x4 acc[4][4];
#pragma unroll
    for (int i = 0; i < 4; ++i)
#pragma unroll
        for (int j = 0; j < 4; ++j) acc[i][j] = (f32x4){0.f, 0.f, 0.f, 0.f};

    for (int k0 = 0; k0 < DIM; k0 += 32) {
        __syncthreads();
        glds16(gA + k0,            lA);
        glds16(gA + 16 * DIM + k0, lA + 16 * 32);
        glds16(gW + k0,            lW);
        glds16(gW + 16 * DIM + k0, lW + 16 * 32);
        __syncthreads();

        bf16x8 af[4], bfr[4];
#pragma unroll
        for (int mt = 0; mt < 4; ++mt)
            af[mt] = *(const bf16x8*)&As[(wm + mt * 16 + ln) * 32 + quad * 8];
#pragma unroll
        for (int nt = 0; nt < 4; ++nt)
            bfr[nt] = *(const bf16x8*)&Bs[(wn + nt * 16 + ln) * 32 + quad * 8];
#pragma unroll
        for (int mt = 0; mt < 4; ++mt)
#pragma unroll
            for (int nt = 0; nt < 4; ++nt)
                acc[mt][nt] = MFMA_BF16(af[mt], bfr[nt], acc[mt][nt]);
    }

    if (z == 2) {
        // V epilogue: store transposed per head -> Vt_g[((b*16+h)*64+e)*SEQ + s]
#pragma unroll
        for (int nt = 0; nt < 4; ++nt) {
            const int col = n0 + wn + nt * 16 + ln;       // d
            const int h2 = col >> 6, e = col & 63;
            const float bv = (float)bi[col];
#pragma unroll
            for (int mt = 0; mt < 4; ++mt) {
                const int row = m0 + wm + mt * 16 + quad * 4;
                const int bb = row >> 11, s = row & 2047;
                bf16x4 o = {(bf16)(acc[mt][nt][0] + bv), (bf16)(acc[mt][nt][1] + bv),
                            (bf16)(acc[mt][nt][2] + bv), (bf16)(acc[mt][nt][3] + bv)};
                *(bf16x4*)&Vtg[((size_t)((bb * 16 + h2) * 64 + e)) * SEQ + s] = o;
            }
        }
    } else {
        bf16* C = (z == 0) ? C0 : C1;
#pragma unroll
        for (int nt = 0; nt < 4; ++nt) {
            const int col = n0 + wn + nt * 16 + ln;
            const float bv = (float)bi[col];
#pragma unroll
            for (int mt = 0; mt < 4; ++mt)
#pragma unroll
                for (int r = 0; r < 4; ++r) {
                    const int row = m0 + wm + mt * 16 + quad * 4 + r;
                    C[(size_t)row * DIM + col] = (bf16)(acc[mt][nt][r] + bv);
                }
        }
    }
}

// ---------------------------------------------------------------------------
// Output GEMM (R7 structure): 64x128 tile -> 512 blocks = 2/CU. C = A@Wo^T+bo.
// ---------------------------------------------------------------------------
__global__ __launch_bounds__(256, 4) void gemm_out_kernel(
    const bf16* __restrict__ A, const bf16* __restrict__ W,
    const bf16* __restrict__ bi, void* __restrict__ C,
    const int* __restrict__ flags)
{
    __shared__ bf16 As[64 * 32];
    __shared__ bf16 Bs[128 * 32];

    const int t = threadIdx.x;
    const bool of32 = flags[0] != 0;

    const int n0 = blockIdx.x * 128;
    const int m0 = blockIdx.y * 64;
    const int w    = t >> 6;
    const int lane = t & 63;
    const int ln   = t & 15;
    const int quad = (t >> 4) & 3;
    const int wm   = (w & 1) * 32;
    const int wn   = (w >> 1) * 64;

    const int arow = w * 16 + (lane >> 2);
    const int wrow = w * 32 + (lane >> 2);
    const int scol = (lane & 3) * 8;
    const bf16* gA = A + (size_t)(m0 + arow) * DIM + scol;
    const bf16* gW = W + (size_t)(n0 + wrow) * DIM + scol;
    bf16* lA = &As[(w * 16) * 32];
    bf16* lW = &Bs[(w * 32) * 32];

    f32x4 acc[2][4];
#pragma unroll
    for (int i = 0; i < 2; ++i)
#pragma unroll
        for (int j = 0; j < 4; ++j) acc[i][j] = (f32x4){0.f, 0.f, 0.f, 0.f};

    for (int k0 = 0; k0 < DIM; k0 += 32) {
        __syncthreads();
        glds16(gA + k0,            lA);
        glds16(gW + k0,            lW);
        glds16(gW + 16 * DIM + k0, lW + 16 * 32);
        __syncthreads();

        bf16x8 af[2], bfr[4];
#pragma unroll
        for (int mt = 0; mt < 2; ++mt)
            af[mt] = *(const bf16x8*)&As[(wm + mt * 16 + ln) * 32 + quad * 8];
#pragma unroll
        for (int nt = 0; nt < 4; ++nt)
            bfr[nt] = *(const bf16x8*)&Bs[(wn + nt * 16 + ln) * 32 + quad * 8];
#pragma unroll
        for (int mt = 0; mt < 2; ++mt)
#pragma unroll
            for (int nt = 0; nt < 4; ++nt)
                acc[mt][nt] = MFMA_BF16(af[mt], bfr[nt], acc[mt][nt]);
    }

#pragma unroll
    for (int nt = 0; nt < 4; ++nt) {
        const int col = n0 + wn + nt * 16 + ln;
        const float bv = (float)bi[col];
#pragma unroll
        for (int mt = 0; mt < 2; ++mt)
#pragma unroll
            for (int r = 0; r < 4; ++r) {
                const int row = m0 + wm + mt * 16 + quad * 4 + r;
                if (of32) ((float*)C)[(size_t)row * DIM + col] = acc[mt][nt][r] + bv;
                else      ((bf16*)C)[(size_t)row * DIM + col] = (bf16)(acc[mt][nt][r] + bv);
            }
    }
}

// ---------------------------------------------------------------------------
// Flash attention: R4's proven compute body (P through per-wave swizzled LDS,
// 104 VGPR) with SINGLE-buffered K/V (dbuf proven null R1-vs-R4) ->
// LDS = 16(K)+16(V)+16(Ps) = 48 KB -> 3 blocks/CU at launch_bounds(256,3).
// This is the clean occupancy test R8 failed to run (R8's in-reg-P variant
// spilled: 607 MB scratch writes at a 128-VGPR cap). Same per-block
// compute:staging ratio as the 83us baseline; 1.5x resident waves.
//   Ks[r][e]: phys chunk c holds logical chunk c^(r&7)
//   Vt[e][k]: phys chunk c holds logical chunk c^(e&15)
//   Ps: per-wave 16q x 128k, 8B-slot XOR swizzle (slot s at s^((ln&15)<<1))
// ---------------------------------------------------------------------------
__global__ __launch_bounds__(256, 3) void attn_kernel(
    const bf16* __restrict__ Q, const bf16* __restrict__ K,
    const bf16* __restrict__ Vtg, bf16* __restrict__ O)
{
    const int qt = blockIdx.x;        // 0..15: 128 q-rows
    const int bh = blockIdx.y;        // 0..31
    const int b  = bh >> 4;
    const int h  = bh & 15;

    __shared__ bf16 Ks[128 * 64];     // swizzled, stride 64   (16 KB)
    __shared__ bf16 Vt[64 * 128];     // swizzled, stride 128  (16 KB)
    __shared__ bf16 Ps[4 * 16 * 128]; // per-wave 16q x 128k, swizzled (16 KB)

    const int t    = threadIdx.x;
    const int w    = t >> 6;
    const int lane = t & 63;
    const int ln   = lane & 15;
    const int quad = lane >> 4;

    const int q0 = qt * 128;

    const float sc = 0.125f * 1.44269504089f;   // 1/sqrt(HD) * log2(e)
    bf16x8 qf[2][2];
#pragma unroll
    for (int g = 0; g < 2; ++g) {
        const bf16* qrow = Q + (size_t)(b * SEQ + q0 + w * 32 + g * 16 + ln) * DIM + h * HDIM;
        qf[g][0] = *(const bf16x8*)(qrow + quad * 8);
        qf[g][1] = *(const bf16x8*)(qrow + 32 + quad * 8);
#pragma unroll
        for (int i = 0; i < 8; ++i) {
            qf[g][0][i] = (bf16)((float)qf[g][0][i] * sc);
            qf[g][1][i] = (bf16)((float)qf[g][1][i] * sc);
        }
    }

    f32x4 o_acc[2][4];
#pragma unroll
    for (int g = 0; g < 2; ++g)
#pragma unroll
        for (int c = 0; c < 4; ++c) o_acc[g][c] = (f32x4){0.f, 0.f, 0.f, 0.f};
    float m_s[2] = {-1e30f, -1e30f};
    float l_s[2] = {0.f, 0.f};

    // K staging: wave w, instr i stages rows w*32+i*8 .. +7 (8 rows x 8 chunks)
    const int kr_off = lane >> 3;               // row-in-group 0..7
    const int k_lc   = (lane & 7) ^ kr_off;     // logical chunk (source swizzle)
    // V staging: wave w, instr i stages e-rows w*16+i*4 .. +3 (4 rows x 16 chunks)
    const int ve_off = lane >> 4;               // 0..3
    const int v_pc   = lane & 15;               // phys chunk
    const size_t vrowbase = (size_t)((b * 16 + h) * 64);

    const int psbase = (w * 16 + ln) * 128;     // per-wave row, stride 128
    const int pmask  = (ln & 15) << 1;          // 8B-slot XOR swizzle (even)

    for (int kb = 0; kb < SEQ; kb += 128) {
        __syncthreads();              // prev-iter Ks/Vt reads complete
#pragma unroll
        for (int i = 0; i < 4; ++i) {
            const int r = w * 32 + i * 8 + kr_off;
            glds16(K + (size_t)(b * SEQ + kb + r) * DIM + h * HDIM + k_lc * 8,
                   &Ks[(w * 32 + i * 8) * 64]);
        }
#pragma unroll
        for (int i = 0; i < 4; ++i) {
            const int e2 = w * 16 + i * 4 + ve_off;
            const int lc = v_pc ^ (i * 4 + ve_off);
            glds16(Vtg + (vrowbase + e2) * SEQ + kb + lc * 8,
                   &Vt[(w * 16 + i * 4) * 128]);
        }
        __syncthreads();              // drains vmcnt: tiles visible

        // ---- S^T = K·Q^T for both q-groups; K-frags loaded once
        f32x4 sa0[8], sa1[8];
#pragma unroll
        for (int nt = 0; nt < 8; ++nt) {
            const int rr = (nt * 16 + ln) * 64;
            const bf16x8 kf0 = *(const bf16x8*)&Ks[rr + ((quad ^ (ln & 7)) << 3)];
            const bf16x8 kf1 = *(const bf16x8*)&Ks[rr + (((quad + 4) ^ (ln & 7)) << 3)];
            f32x4 z0 = (f32x4){0.f, 0.f, 0.f, 0.f};
            z0 = MFMA_BF16(kf0, qf[0][0], z0);
            z0 = MFMA_BF16(kf1, qf[0][1], z0);
            sa0[nt] = z0;
            f32x4 z1 = (f32x4){0.f, 0.f, 0.f, 0.f};
            z1 = MFMA_BF16(kf0, qf[1][0], z1);
            z1 = MFMA_BF16(kf1, qf[1][1], z1);
            sa1[nt] = z1;
        }

        // ---- online softmax (scalar state per lane, q = w*32 + g*16 + ln)
        float al[2];
#pragma unroll
        for (int g = 0; g < 2; ++g) {
            f32x4* sa = g ? sa1 : sa0;
            float m8[8];
#pragma unroll
            for (int nt = 0; nt < 8; ++nt)
                m8[nt] = fmaxf(fmaxf(sa[nt][0], sa[nt][1]), fmaxf(sa[nt][2], sa[nt][3]));
            float mx = fmaxf(fmaxf(fmaxf(m8[0], m8[1]), fmaxf(m8[2], m8[3])),
                             fmaxf(fmaxf(m8[4], m8[5]), fmaxf(m8[6], m8[7])));
            mx = fmaxf(mx, __shfl_xor(mx, 16));
            mx = fmaxf(mx, __shfl_xor(mx, 32));
            const float mn = fmaxf(m_s[g], mx);
            al[g] = exp2f(m_s[g] - mn);
            m_s[g] = mn;
            float r8[8];
#pragma unroll
            for (int nt = 0; nt < 8; ++nt) {
                float p0 = exp2f(sa[nt][0] - mn);
                float p1 = exp2f(sa[nt][1] - mn);
                float p2 = exp2f(sa[nt][2] - mn);
                float p3 = exp2f(sa[nt][3] - mn);
                sa[nt][0] = p0; sa[nt][1] = p1; sa[nt][2] = p2; sa[nt][3] = p3;
                r8[nt] = (p0 + p1) + (p2 + p3);
            }
            float rs = ((r8[0] + r8[1]) + (r8[2] + r8[3])) +
                       ((r8[4] + r8[5]) + (r8[6] + r8[7]));
            rs += __shfl_xor(rs, 16);
            rs += __shfl_xor(rs, 32);
            l_s[g] = l_s[g] * al[g] + rs;
#pragma unroll
            for (int r = 0; r < 4; ++r) {
                const float alr = __shfl(al[g], quad * 4 + r);
#pragma unroll
                for (int c = 0; c < 4; ++c) o_acc[g][c][r] *= alr;
            }
        }

        // ---- P g0 -> Ps (per-wave rows, swizzled slots)
#pragma unroll
        for (int nt = 0; nt < 8; ++nt) {
            bf16x4 pk = {(bf16)sa0[nt][0], (bf16)sa0[nt][1],
                         (bf16)sa0[nt][2], (bf16)sa0[nt][3]};
            *(bf16x4*)&Ps[psbase + (((nt * 4 + quad) ^ pmask) << 2)] = pk;
        }
        __asm__ volatile("s_waitcnt lgkmcnt(0)" ::: "memory");
        bf16x8 pf0[4];
#pragma unroll
        for (int kc = 0; kc < 4; ++kc)
            pf0[kc] = *(const bf16x8*)&Ps[psbase + (((kc * 8 + quad * 2) ^ pmask) << 2)];
        __asm__ volatile("s_waitcnt lgkmcnt(0)" ::: "memory");
        // ---- P g1 -> Ps (same rows; overlaps g0 MFMAs below)
#pragma unroll
        for (int nt = 0; nt < 8; ++nt) {
            bf16x4 pk = {(bf16)sa1[nt][0], (bf16)sa1[nt][1],
                         (bf16)sa1[nt][2], (bf16)sa1[nt][3]};
            *(bf16x4*)&Ps[psbase + (((nt * 4 + quad) ^ pmask) << 2)] = pk;
        }
        // ---- V frags (swizzled), loaded once for both groups
        bf16x8 vf[4][4];
#pragma unroll
        for (int kc = 0; kc < 4; ++kc)
#pragma unroll
            for (int c = 0; c < 4; ++c) {
                const int e = c * 16 + ln;
                const int pc = (kc * 4 + quad) ^ ln;
                vf[kc][c] = *(const bf16x8*)&Vt[e * 128 + pc * 8];
            }
        __asm__ volatile("s_waitcnt lgkmcnt(0)" ::: "memory");

#pragma unroll
        for (int kc = 0; kc < 4; ++kc)
#pragma unroll
            for (int c = 0; c < 4; ++c)
                o_acc[0][c] = MFMA_BF16(pf0[kc], vf[kc][c], o_acc[0][c]);
        bf16x8 pf1[4];
#pragma unroll
        for (int kc = 0; kc < 4; ++kc)
            pf1[kc] = *(const bf16x8*)&Ps[psbase + (((kc * 8 + quad * 2) ^ pmask) << 2)];
        __asm__ volatile("s_waitcnt lgkmcnt(0)" ::: "memory");
#pragma unroll
        for (int kc = 0; kc < 4; ++kc)
#pragma unroll
            for (int c = 0; c < 4; ++c)
                o_acc[1][c] = MFMA_BF16(pf1[kc], vf[kc][c], o_acc[1][c]);
    }

    // ---- epilogue: normalize, store bf16
#pragma unroll
    for (int g = 0; g < 2; ++g) {
        const float linv = 1.0f / l_s[g];
#pragma unroll
        for (int r = 0; r < 4; ++r) {
            const float lr = __shfl(linv, quad * 4 + r);
            const size_t rowoff =
                (size_t)(b * SEQ + q0 + w * 32 + g * 16 + quad * 4 + r) * DIM + h * HDIM;
#pragma unroll
            for (int c = 0; c < 4; ++c)
                O[rowoff + c * 16 + ln] = (bf16)(o_acc[g][c][r] * lr);
        }
    }
}

extern "C" void kernel_launch(void* const* d_in, const int* in_sizes, int n_in,
                              void* d_out, int out_size, void* d_ws, size_t ws_size,
                              hipStream_t stream) {
    // ws layout (bf16 elems): Qb,Kb,Vtg (4.19M each), qc,kc,vc (4.19M each;
    // qc is re-used as Ob after gemm_qkv has consumed it), Wq..Wo (1.05M
    // each), biases (1K each), flags. Total ~59 MB.
    const size_t NM = (size_t)MROWS * DIM;     // 4194304
    const size_t NW = (size_t)DIM * DIM;       // 1048576
    bf16* Qb  = (bf16*)d_ws;
    bf16* Kb  = Qb + NM;
    bf16* Vtg = Kb + NM;
    bf16* qc  = Vtg + NM;
    bf16* kc  = qc + NM;
    bf16* vc  = kc + NM;
    bf16* Wqc = vc + NM;
    bf16* Wkc = Wqc + NW;
    bf16* Wvc = Wkc + NW;
    bf16* Woc = Wvc + NW;
    bf16* bqc = Woc + NW;
    bf16* bkc = bqc + 1024;
    bf16* bvc = bkc + 1024;
    bf16* boc = bvc + 1024;
    int*  flags = (int*)(boc + 1024);
    bf16* Ob  = qc;   // alias: qc dead after gemm_qkv, Ob written by attn

    convert_kernel<<<dim3(2052), 256, 0, stream>>>(
        d_in[0], d_in[1], d_in[2],
        d_in[3], d_in[5], d_in[7], d_in[9],
        d_in[4], d_in[6], d_in[8], d_in[10],
        qc, kc, vc, Wqc, Wkc, Wvc, Woc, bqc, bkc, bvc, boc, flags);

    gemm_qkv_kernel<<<dim3(DIM / 128, MROWS / 128, 3), 256, 0, stream>>>(
        qc, Wqc, bqc, Qb,
        kc, Wkc, bkc, Kb,
        vc, Wvc, bvc, Vtg);

    attn_kernel<<<dim3(SEQ / 128, BATCH * 16), 256, 0, stream>>>(Qb, Kb, Vtg, Ob);

    gemm_out_kernel<<<dim3(DIM / 128, MROWS / 64), 256, 0, stream>>>(
        Ob, Woc, boc, d_out, flags);
}

// Round 10
// 259.270 us; speedup vs baseline: 1.6074x; 1.1408x over previous
//
#include <hip/hip_runtime.h>
#include <stdint.h>

typedef __bf16 bf16;
typedef __bf16 bf16x8 __attribute__((ext_vector_type(8)));  // 16B
typedef __bf16 bf16x4 __attribute__((ext_vector_type(4)));  // 8B
typedef float  f32x4  __attribute__((ext_vector_type(4)));

#define MFMA_BF16(a, b, c) __builtin_amdgcn_mfma_f32_16x16x32_bf16((a), (b), (c), 0, 0, 0)

static constexpr int BATCH = 2;
static constexpr int SEQ   = 2048;
static constexpr int DIM   = 1024;
static constexpr int HDIM  = 64;
static constexpr int MROWS = BATCH * SEQ;   // 4096

typedef const __attribute__((address_space(1))) void* gvp;
typedef __attribute__((address_space(3))) void* svp;
__device__ __forceinline__ void glds16(const bf16* g, bf16* l) {
    __builtin_amdgcn_global_load_lds((gvp)(const void*)g, (svp)(void*)l, 16, 0, 0);
}

// scan leading nscan u16 of buffer as bf16; any exponent>=0x89 (|x|>=1024 /
// inf / nan) -> fp32 data misread as bf16 (P~0.46 per elem; deterministic
// across blocks since all scan identical bytes). True bf16 here has |x|<6.
__device__ __forceinline__ int scan_f32(const void* p, int nscan, int t) {
    const unsigned short* s = (const unsigned short*)p;
    int local = 0;
    for (int j = t; j < nscan; j += 256)
        local |= (((s[j] >> 7) & 0xFF) >= 0x89) ? 1 : 0;
    return local;
}

__device__ __forceinline__ bf16x8 cvt8(const float4 a, const float4 b) {
    bf16x8 r = {(bf16)a.x, (bf16)a.y, (bf16)a.z, (bf16)a.w,
                (bf16)b.x, (bf16)b.y, (bf16)b.z, (bf16)b.w};
    return r;
}

// ---------------------------------------------------------------------------
// Convert pass (R7 structure): dtype-adaptive fp32|bf16 -> bf16 workspace
// copies. 2052 blocks, 16 KB/block in 4 rounds.
// ---------------------------------------------------------------------------
__global__ __launch_bounds__(256) void convert_kernel(
    const void* __restrict__ q,  const void* __restrict__ k,  const void* __restrict__ v,
    const void* __restrict__ wq, const void* __restrict__ wk, const void* __restrict__ wv,
    const void* __restrict__ wo,
    const void* __restrict__ b_q, const void* __restrict__ b_k,
    const void* __restrict__ b_v, const void* __restrict__ b_o,
    bf16* __restrict__ qd,  bf16* __restrict__ kd,  bf16* __restrict__ vd,
    bf16* __restrict__ wqd, bf16* __restrict__ wkd, bf16* __restrict__ wvd,
    bf16* __restrict__ wod,
    bf16* __restrict__ bqd, bf16* __restrict__ bkd,
    bf16* __restrict__ bvd, bf16* __restrict__ bod,
    int* __restrict__ flagsOut)
{
    const int bid = blockIdx.x;
    int id, chunk;
    if (bid < 1536)      { id = bid >> 9;                chunk = bid & 511; }
    else if (bid < 2048) { id = 3 + ((bid - 1536) >> 7); chunk = (bid - 1536) & 127; }
    else                 { id = 7 + (bid - 2048);        chunk = 0; }

    const void* src; bf16* dst; int nelem, nscan;
    switch (id) {
        case 0:  src = q;   dst = qd;  nelem = 1 << 22; nscan = 4096; break;
        case 1:  src = k;   dst = kd;  nelem = 1 << 22; nscan = 4096; break;
        case 2:  src = v;   dst = vd;  nelem = 1 << 22; nscan = 4096; break;
        case 3:  src = wq;  dst = wqd; nelem = 1 << 20; nscan = 4096; break;
        case 4:  src = wk;  dst = wkd; nelem = 1 << 20; nscan = 4096; break;
        case 5:  src = wv;  dst = wvd; nelem = 1 << 20; nscan = 4096; break;
        case 6:  src = wo;  dst = wod; nelem = 1 << 20; nscan = 4096; break;
        case 7:  src = b_q; dst = bqd; nelem = 1024;    nscan = 1024; break;
        case 8:  src = b_k; dst = bkd; nelem = 1024;    nscan = 1024; break;
        case 9:  src = b_v; dst = bvd; nelem = 1024;    nscan = 1024; break;
        default: src = b_o; dst = bod; nelem = 1024;    nscan = 1024; break;
    }

    __shared__ int sbad;
    const int t = threadIdx.x;
    if (t == 0) sbad = 0;
    __syncthreads();
    int loc = scan_f32(src, nscan, t);
    if (loc) atomicOr(&sbad, 1);
    __syncthreads();
    const bool f32 = sbad != 0;

    if (id == 0 && chunk == 0 && t == 0) flagsOut[0] = f32 ? 1 : 0;

    if (id < 7) {
        const int base0 = chunk * 8192 + t * 8;
        if (f32) {
            const float* s = (const float*)src;
#pragma unroll
            for (int r = 0; r < 4; ++r) {
                const int base = base0 + r * 2048;
                const float4 a  = *(const float4*)(s + base);
                const float4 b2 = *(const float4*)(s + base + 4);
                *(bf16x8*)(dst + base) = cvt8(a, b2);
            }
        } else {
            const bf16* s = (const bf16*)src;
#pragma unroll
            for (int r = 0; r < 4; ++r) {
                const int base = base0 + r * 2048;
                *(bf16x8*)(dst + base) = *(const bf16x8*)(s + base);
            }
        }
    } else {
        const int base = t * 8;
        if (base < nelem) {
            if (f32) {
                const float* s = (const float*)src + base;
                const float4 a  = *(const float4*)s;
                const float4 b2 = *(const float4*)(s + 4);
                *(bf16x8*)(dst + base) = cvt8(a, b2);
            } else {
                *(bf16x8*)(dst + base) = *(const bf16x8*)((const bf16*)src + base);
            }
        }
    }
}

// ---------------------------------------------------------------------------
// QKV GEMM, all-bf16 (m97 structure): C = A @ W^T + bias. Both operands
// staged via glds16. 128x128 tile, BK=32, 2-barrier K-loop. z==2 (V) stores
// C transposed per head: Vt_g[b][h][e][s], vectorized bf16x4 along s.
// ---------------------------------------------------------------------------
__global__ __launch_bounds__(256, 3) void gemm_qkv_kernel(
    const bf16* __restrict__ A0, const bf16* __restrict__ W0,
    const bf16* __restrict__ b0, bf16* __restrict__ C0,
    const bf16* __restrict__ A1, const bf16* __restrict__ W1,
    const bf16* __restrict__ b1, bf16* __restrict__ C1,
    const bf16* __restrict__ A2, const bf16* __restrict__ W2,
    const bf16* __restrict__ b2, bf16* __restrict__ Vtg)
{
    const int z = blockIdx.z;
    const bf16* A  = (z == 0) ? A0 : (z == 1) ? A1 : A2;
    const bf16* W  = (z == 0) ? W0 : (z == 1) ? W1 : W2;
    const bf16* bi = (z == 0) ? b0 : (z == 1) ? b1 : b2;

    __shared__ bf16 As[128 * 32];
    __shared__ bf16 Bs[128 * 32];

    const int t = threadIdx.x;
    const int n0 = blockIdx.x * 128;
    const int m0 = blockIdx.y * 128;
    const int w    = t >> 6;
    const int lane = t & 63;
    const int ln   = t & 15;
    const int quad = (t >> 4) & 3;
    const int wm   = (w & 1) * 64;
    const int wn   = (w >> 1) * 64;

    const int srow = w * 32 + (lane >> 2);
    const int scol = (lane & 3) * 8;
    const bf16* gA = A + (size_t)(m0 + srow) * DIM + scol;
    const bf16* gW = W + (size_t)(n0 + srow) * DIM + scol;
    bf16* lA = &As[w * 32 * 32];
    bf16* lW = &Bs[w * 32 * 32];

    f32x4 acc[4][4];
#pragma unroll
    for (int i = 0; i < 4; ++i)
#pragma unroll
        for (int j = 0; j < 4; ++j) acc[i][j] = (f32x4){0.f, 0.f, 0.f, 0.f};

    for (int k0 = 0; k0 < DIM; k0 += 32) {
        __syncthreads();
        glds16(gA + k0,            lA);
        glds16(gA + 16 * DIM + k0, lA + 16 * 32);
        glds16(gW + k0,            lW);
        glds16(gW + 16 * DIM + k0, lW + 16 * 32);
        __syncthreads();

        bf16x8 af[4], bfr[4];
#pragma unroll
        for (int mt = 0; mt < 4; ++mt)
            af[mt] = *(const bf16x8*)&As[(wm + mt * 16 + ln) * 32 + quad * 8];
#pragma unroll
        for (int nt = 0; nt < 4; ++nt)
            bfr[nt] = *(const bf16x8*)&Bs[(wn + nt * 16 + ln) * 32 + quad * 8];
#pragma unroll
        for (int mt = 0; mt < 4; ++mt)
#pragma unroll
            for (int nt = 0; nt < 4; ++nt)
                acc[mt][nt] = MFMA_BF16(af[mt], bfr[nt], acc[mt][nt]);
    }

    if (z == 2) {
        // V epilogue: store transposed per head -> Vt_g[((b*16+h)*64+e)*SEQ + s]
#pragma unroll
        for (int nt = 0; nt < 4; ++nt) {
            const int col = n0 + wn + nt * 16 + ln;       // d
            const int h2 = col >> 6, e = col & 63;
            const float bv = (float)bi[col];
#pragma unroll
            for (int mt = 0; mt < 4; ++mt) {
                const int row = m0 + wm + mt * 16 + quad * 4;
                const int bb = row >> 11, s = row & 2047;
                bf16x4 o = {(bf16)(acc[mt][nt][0] + bv), (bf16)(acc[mt][nt][1] + bv),
                            (bf16)(acc[mt][nt][2] + bv), (bf16)(acc[mt][nt][3] + bv)};
                *(bf16x4*)&Vtg[((size_t)((bb * 16 + h2) * 64 + e)) * SEQ + s] = o;
            }
        }
    } else {
        bf16* C = (z == 0) ? C0 : C1;
#pragma unroll
        for (int nt = 0; nt < 4; ++nt) {
            const int col = n0 + wn + nt * 16 + ln;
            const float bv = (float)bi[col];
#pragma unroll
            for (int mt = 0; mt < 4; ++mt)
#pragma unroll
                for (int r = 0; r < 4; ++r) {
                    const int row = m0 + wm + mt * 16 + quad * 4 + r;
                    C[(size_t)row * DIM + col] = (bf16)(acc[mt][nt][r] + bv);
                }
        }
    }
}

// ---------------------------------------------------------------------------
// Output GEMM (R7 structure): 64x128 tile -> 512 blocks = 2/CU. C = A@Wo^T+bo.
// ---------------------------------------------------------------------------
__global__ __launch_bounds__(256, 4) void gemm_out_kernel(
    const bf16* __restrict__ A, const bf16* __restrict__ W,
    const bf16* __restrict__ bi, void* __restrict__ C,
    const int* __restrict__ flags)
{
    __shared__ bf16 As[64 * 32];
    __shared__ bf16 Bs[128 * 32];

    const int t = threadIdx.x;
    const bool of32 = flags[0] != 0;

    const int n0 = blockIdx.x * 128;
    const int m0 = blockIdx.y * 64;
    const int w    = t >> 6;
    const int lane = t & 63;
    const int ln   = t & 15;
    const int quad = (t >> 4) & 3;
    const int wm   = (w & 1) * 32;
    const int wn   = (w >> 1) * 64;

    const int arow = w * 16 + (lane >> 2);
    const int wrow = w * 32 + (lane >> 2);
    const int scol = (lane & 3) * 8;
    const bf16* gA = A + (size_t)(m0 + arow) * DIM + scol;
    const bf16* gW = W + (size_t)(n0 + wrow) * DIM + scol;
    bf16* lA = &As[(w * 16) * 32];
    bf16* lW = &Bs[(w * 32) * 32];

    f32x4 acc[2][4];
#pragma unroll
    for (int i = 0; i < 2; ++i)
#pragma unroll
        for (int j = 0; j < 4; ++j) acc[i][j] = (f32x4){0.f, 0.f, 0.f, 0.f};

    for (int k0 = 0; k0 < DIM; k0 += 32) {
        __syncthreads();
        glds16(gA + k0,            lA);
        glds16(gW + k0,            lW);
        glds16(gW + 16 * DIM + k0, lW + 16 * 32);
        __syncthreads();

        bf16x8 af[2], bfr[4];
#pragma unroll
        for (int mt = 0; mt < 2; ++mt)
            af[mt] = *(const bf16x8*)&As[(wm + mt * 16 + ln) * 32 + quad * 8];
#pragma unroll
        for (int nt = 0; nt < 4; ++nt)
            bfr[nt] = *(const bf16x8*)&Bs[(wn + nt * 16 + ln) * 32 + quad * 8];
#pragma unroll
        for (int mt = 0; mt < 2; ++mt)
#pragma unroll
            for (int nt = 0; nt < 4; ++nt)
                acc[mt][nt] = MFMA_BF16(af[mt], bfr[nt], acc[mt][nt]);
    }

#pragma unroll
    for (int nt = 0; nt < 4; ++nt) {
        const int col = n0 + wn + nt * 16 + ln;
        const float bv = (float)bi[col];
#pragma unroll
        for (int mt = 0; mt < 2; ++mt)
#pragma unroll
            for (int r = 0; r < 4; ++r) {
                const int row = m0 + wm + mt * 16 + quad * 4 + r;
                if (of32) ((float*)C)[(size_t)row * DIM + col] = acc[mt][nt][r] + bv;
                else      ((bf16*)C)[(size_t)row * DIM + col] = (bf16)(acc[mt][nt][r] + bv);
            }
    }
}

// ---------------------------------------------------------------------------
// Flash attention: R4's proven compute body (P through per-wave swizzled LDS),
// single-buffered K/V, LDS = 16(K)+16(V)+16(Ps) = 48 KB. NO min-waves hint:
// __launch_bounds__(256) only — R8/R9 proved an explicit min-waves arg makes
// hipcc over-restrict VGPRs (64/84 caps) and spill (607/88 MB scratch).
// Occupancy raise comes from the LDS cut alone: 160/48 = 3 blocks/CU with
// free register allocation (~104 VGPR, no spill).
//   Ks[r][e]: phys chunk c holds logical chunk c^(r&7)
//   Vt[e][k]: phys chunk c holds logical chunk c^(e&15)
//   Ps: per-wave 16q x 128k, 8B-slot XOR swizzle (slot s at s^((ln&15)<<1))
// ---------------------------------------------------------------------------
__global__ __launch_bounds__(256) void attn_kernel(
    const bf16* __restrict__ Q, const bf16* __restrict__ K,
    const bf16* __restrict__ Vtg, bf16* __restrict__ O)
{
    const int qt = blockIdx.x;        // 0..15: 128 q-rows
    const int bh = blockIdx.y;        // 0..31
    const int b  = bh >> 4;
    const int h  = bh & 15;

    __shared__ bf16 Ks[128 * 64];     // swizzled, stride 64   (16 KB)
    __shared__ bf16 Vt[64 * 128];     // swizzled, stride 128  (16 KB)
    __shared__ bf16 Ps[4 * 16 * 128]; // per-wave 16q x 128k, swizzled (16 KB)

    const int t    = threadIdx.x;
    const int w    = t >> 6;
    const int lane = t & 63;
    const int ln   = lane & 15;
    const int quad = lane >> 4;

    const int q0 = qt * 128;

    const float sc = 0.125f * 1.44269504089f;   // 1/sqrt(HD) * log2(e)
    bf16x8 qf[2][2];
#pragma unroll
    for (int g = 0; g < 2; ++g) {
        const bf16* qrow = Q + (size_t)(b * SEQ + q0 + w * 32 + g * 16 + ln) * DIM + h * HDIM;
        qf[g][0] = *(const bf16x8*)(qrow + quad * 8);
        qf[g][1] = *(const bf16x8*)(qrow + 32 + quad * 8);
#pragma unroll
        for (int i = 0; i < 8; ++i) {
            qf[g][0][i] = (bf16)((float)qf[g][0][i] * sc);
            qf[g][1][i] = (bf16)((float)qf[g][1][i] * sc);
        }
    }

    f32x4 o_acc[2][4];
#pragma unroll
    for (int g = 0; g < 2; ++g)
#pragma unroll
        for (int c = 0; c < 4; ++c) o_acc[g][c] = (f32x4){0.f, 0.f, 0.f, 0.f};
    float m_s[2] = {-1e30f, -1e30f};
    float l_s[2] = {0.f, 0.f};

    // K staging: wave w, instr i stages rows w*32+i*8 .. +7 (8 rows x 8 chunks)
    const int kr_off = lane >> 3;               // row-in-group 0..7
    const int k_lc   = (lane & 7) ^ kr_off;     // logical chunk (source swizzle)
    // V staging: wave w, instr i stages e-rows w*16+i*4 .. +3 (4 rows x 16 chunks)
    const int ve_off = lane >> 4;               // 0..3
    const int v_pc   = lane & 15;               // phys chunk
    const size_t vrowbase = (size_t)((b * 16 + h) * 64);

    const int psbase = (w * 16 + ln) * 128;     // per-wave row, stride 128
    const int pmask  = (ln & 15) << 1;          // 8B-slot XOR swizzle (even)

    for (int kb = 0; kb < SEQ; kb += 128) {
        __syncthreads();              // prev-iter Ks/Vt reads complete
#pragma unroll
        for (int i = 0; i < 4; ++i) {
            const int r = w * 32 + i * 8 + kr_off;
            glds16(K + (size_t)(b * SEQ + kb + r) * DIM + h * HDIM + k_lc * 8,
                   &Ks[(w * 32 + i * 8) * 64]);
        }
#pragma unroll
        for (int i = 0; i < 4; ++i) {
            const int e2 = w * 16 + i * 4 + ve_off;
            const int lc = v_pc ^ (i * 4 + ve_off);
            glds16(Vtg + (vrowbase + e2) * SEQ + kb + lc * 8,
                   &Vt[(w * 16 + i * 4) * 128]);
        }
        __syncthreads();              // drains vmcnt: tiles visible

        // ---- S^T = K·Q^T for both q-groups; K-frags loaded once
        f32x4 sa0[8], sa1[8];
#pragma unroll
        for (int nt = 0; nt < 8; ++nt) {
            const int rr = (nt * 16 + ln) * 64;
            const bf16x8 kf0 = *(const bf16x8*)&Ks[rr + ((quad ^ (ln & 7)) << 3)];
            const bf16x8 kf1 = *(const bf16x8*)&Ks[rr + (((quad + 4) ^ (ln & 7)) << 3)];
            f32x4 z0 = (f32x4){0.f, 0.f, 0.f, 0.f};
            z0 = MFMA_BF16(kf0, qf[0][0], z0);
            z0 = MFMA_BF16(kf1, qf[0][1], z0);
            sa0[nt] = z0;
            f32x4 z1 = (f32x4){0.f, 0.f, 0.f, 0.f};
            z1 = MFMA_BF16(kf0, qf[1][0], z1);
            z1 = MFMA_BF16(kf1, qf[1][1], z1);
            sa1[nt] = z1;
        }

        // ---- online softmax (scalar state per lane, q = w*32 + g*16 + ln)
        float al[2];
#pragma unroll
        for (int g = 0; g < 2; ++g) {
            f32x4* sa = g ? sa1 : sa0;
            float m8[8];
#pragma unroll
            for (int nt = 0; nt < 8; ++nt)
                m8[nt] = fmaxf(fmaxf(sa[nt][0], sa[nt][1]), fmaxf(sa[nt][2], sa[nt][3]));
            float mx = fmaxf(fmaxf(fmaxf(m8[0], m8[1]), fmaxf(m8[2], m8[3])),
                             fmaxf(fmaxf(m8[4], m8[5]), fmaxf(m8[6], m8[7])));
            mx = fmaxf(mx, __shfl_xor(mx, 16));
            mx = fmaxf(mx, __shfl_xor(mx, 32));
            const float mn = fmaxf(m_s[g], mx);
            al[g] = exp2f(m_s[g] - mn);
            m_s[g] = mn;
            float r8[8];
#pragma unroll
            for (int nt = 0; nt < 8; ++nt) {
                float p0 = exp2f(sa[nt][0] - mn);
                float p1 = exp2f(sa[nt][1] - mn);
                float p2 = exp2f(sa[nt][2] - mn);
                float p3 = exp2f(sa[nt][3] - mn);
                sa[nt][0] = p0; sa[nt][1] = p1; sa[nt][2] = p2; sa[nt][3] = p3;
                r8[nt] = (p0 + p1) + (p2 + p3);
            }
            float rs = ((r8[0] + r8[1]) + (r8[2] + r8[3])) +
                       ((r8[4] + r8[5]) + (r8[6] + r8[7]));
            rs += __shfl_xor(rs, 16);
            rs += __shfl_xor(rs, 32);
            l_s[g] = l_s[g] * al[g] + rs;
#pragma unroll
            for (int r = 0; r < 4; ++r) {
                const float alr = __shfl(al[g], quad * 4 + r);
#pragma unroll
                for (int c = 0; c < 4; ++c) o_acc[g][c][r] *= alr;
            }
        }

        // ---- P g0 -> Ps (per-wave rows, swizzled slots)
#pragma unroll
        for (int nt = 0; nt < 8; ++nt) {
            bf16x4 pk = {(bf16)sa0[nt][0], (bf16)sa0[nt][1],
                         (bf16)sa0[nt][2], (bf16)sa0[nt][3]};
            *(bf16x4*)&Ps[psbase + (((nt * 4 + quad) ^ pmask) << 2)] = pk;
        }
        __asm__ volatile("s_waitcnt lgkmcnt(0)" ::: "memory");
        bf16x8 pf0[4];
#pragma unroll
        for (int kc = 0; kc < 4; ++kc)
            pf0[kc] = *(const bf16x8*)&Ps[psbase + (((kc * 8 + quad * 2) ^ pmask) << 2)];
        __asm__ volatile("s_waitcnt lgkmcnt(0)" ::: "memory");
        // ---- P g1 -> Ps (same rows; overlaps g0 MFMAs below)
#pragma unroll
        for (int nt = 0; nt < 8; ++nt) {
            bf16x4 pk = {(bf16)sa1[nt][0], (bf16)sa1[nt][1],
                         (bf16)sa1[nt][2], (bf16)sa1[nt][3]};
            *(bf16x4*)&Ps[psbase + (((nt * 4 + quad) ^ pmask) << 2)] = pk;
        }
        // ---- V frags (swizzled), loaded once for both groups
        bf16x8 vf[4][4];
#pragma unroll
        for (int kc = 0; kc < 4; ++kc)
#pragma unroll
            for (int c = 0; c < 4; ++c) {
                const int e = c * 16 + ln;
                const int pc = (kc * 4 + quad) ^ ln;
                vf[kc][c] = *(const bf16x8*)&Vt[e * 128 + pc * 8];
            }
        __asm__ volatile("s_waitcnt lgkmcnt(0)" ::: "memory");

#pragma unroll
        for (int kc = 0; kc < 4; ++kc)
#pragma unroll
            for (int c = 0; c < 4; ++c)
                o_acc[0][c] = MFMA_BF16(pf0[kc], vf[kc][c], o_acc[0][c]);
        bf16x8 pf1[4];
#pragma unroll
        for (int kc = 0; kc < 4; ++kc)
            pf1[kc] = *(const bf16x8*)&Ps[psbase + (((kc * 8 + quad * 2) ^ pmask) << 2)];
        __asm__ volatile("s_waitcnt lgkmcnt(0)" ::: "memory");
#pragma unroll
        for (int kc = 0; kc < 4; ++kc)
#pragma unroll
            for (int c = 0; c < 4; ++c)
                o_acc[1][c] = MFMA_BF16(pf1[kc], vf[kc][c], o_acc[1][c]);
    }

    // ---- epilogue: normalize, store bf16
#pragma unroll
    for (int g = 0; g < 2; ++g) {
        const float linv = 1.0f / l_s[g];
#pragma unroll
        for (int r = 0; r < 4; ++r) {
            const float lr = __shfl(linv, quad * 4 + r);
            const size_t rowoff =
                (size_t)(b * SEQ + q0 + w * 32 + g * 16 + quad * 4 + r) * DIM + h * HDIM;
#pragma unroll
            for (int c = 0; c < 4; ++c)
                O[rowoff + c * 16 + ln] = (bf16)(o_acc[g][c][r] * lr);
        }
    }
}

extern "C" void kernel_launch(void* const* d_in, const int* in_sizes, int n_in,
                              void* d_out, int out_size, void* d_ws, size_t ws_size,
                              hipStream_t stream) {
    // ws layout (bf16 elems): Qb,Kb,Vtg (4.19M each), qc,kc,vc (4.19M each;
    // qc is re-used as Ob after gemm_qkv has consumed it), Wq..Wo (1.05M
    // each), biases (1K each), flags. Total ~59 MB.
    const size_t NM = (size_t)MROWS * DIM;     // 4194304
    const size_t NW = (size_t)DIM * DIM;       // 1048576
    bf16* Qb  = (bf16*)d_ws;
    bf16* Kb  = Qb + NM;
    bf16* Vtg = Kb + NM;
    bf16* qc  = Vtg + NM;
    bf16* kc  = qc + NM;
    bf16* vc  = kc + NM;
    bf16* Wqc = vc + NM;
    bf16* Wkc = Wqc + NW;
    bf16* Wvc = Wkc + NW;
    bf16* Woc = Wvc + NW;
    bf16* bqc = Woc + NW;
    bf16* bkc = bqc + 1024;
    bf16* bvc = bkc + 1024;
    bf16* boc = bvc + 1024;
    int*  flags = (int*)(boc + 1024);
    bf16* Ob  = qc;   // alias: qc dead after gemm_qkv, Ob written by attn

    convert_kernel<<<dim3(2052), 256, 0, stream>>>(
        d_in[0], d_in[1], d_in[2],
        d_in[3], d_in[5], d_in[7], d_in[9],
        d_in[4], d_in[6], d_in[8], d_in[10],
        qc, kc, vc, Wqc, Wkc, Wvc, Woc, bqc, bkc, bvc, boc, flags);

    gemm_qkv_kernel<<<dim3(DIM / 128, MROWS / 128, 3), 256, 0, stream>>>(
        qc, Wqc, bqc, Qb,
        kc, Wkc, bkc, Kb,
        vc, Wvc, bvc, Vtg);

    attn_kernel<<<dim3(SEQ / 128, BATCH * 16), 256, 0, stream>>>(Qb, Kb, Vtg, Ob);

    gemm_out_kernel<<<dim3(DIM / 128, MROWS / 64), 256, 0, stream>>>(
        Ob, Woc, boc, d_out, flags);
}

// Round 11
// 248.510 us; speedup vs baseline: 1.6770x; 1.0433x over previous
//
#include <hip/hip_runtime.h>
#include <stdint.h>

typedef __bf16 bf16;
typedef __bf16 bf16x8 __attribute__((ext_vector_type(8)));  // 16B
typedef __bf16 bf16x4 __attribute__((ext_vector_type(4)));  // 8B
typedef float  f32x4  __attribute__((ext_vector_type(4)));

#define MFMA_BF16(a, b, c) __builtin_amdgcn_mfma_f32_16x16x32_bf16((a), (b), (c), 0, 0, 0)

static constexpr int BATCH = 2;
static constexpr int SEQ   = 2048;
static constexpr int DIM   = 1024;
static constexpr int HDIM  = 64;
static constexpr int MROWS = BATCH * SEQ;   // 4096

typedef const __attribute__((address_space(1))) void* gvp;
typedef __attribute__((address_space(3))) void* svp;
__device__ __forceinline__ void glds16(const bf16* g, bf16* l) {
    __builtin_amdgcn_global_load_lds((gvp)(const void*)g, (svp)(void*)l, 16, 0, 0);
}

// scan leading nscan u16 of buffer as bf16; any exponent>=0x89 (|x|>=1024 /
// inf / nan) -> fp32 data misread as bf16 (P~0.46 per elem; deterministic
// across blocks since all scan identical bytes). True bf16 here has |x|<6.
__device__ __forceinline__ int scan_f32(const void* p, int nscan, int t) {
    const unsigned short* s = (const unsigned short*)p;
    int local = 0;
    for (int j = t; j < nscan; j += 256)
        local |= (((s[j] >> 7) & 0xFF) >= 0x89) ? 1 : 0;
    return local;
}

__device__ __forceinline__ bf16x8 cvt8(const float4 a, const float4 b) {
    bf16x8 r = {(bf16)a.x, (bf16)a.y, (bf16)a.z, (bf16)a.w,
                (bf16)b.x, (bf16)b.y, (bf16)b.z, (bf16)b.w};
    return r;
}

// ---------------------------------------------------------------------------
// Convert pass (R7 structure): dtype-adaptive fp32|bf16 -> bf16 workspace
// copies. 2052 blocks, 16 KB/block in 4 rounds.
// ---------------------------------------------------------------------------
__global__ __launch_bounds__(256) void convert_kernel(
    const void* __restrict__ q,  const void* __restrict__ k,  const void* __restrict__ v,
    const void* __restrict__ wq, const void* __restrict__ wk, const void* __restrict__ wv,
    const void* __restrict__ wo,
    const void* __restrict__ b_q, const void* __restrict__ b_k,
    const void* __restrict__ b_v, const void* __restrict__ b_o,
    bf16* __restrict__ qd,  bf16* __restrict__ kd,  bf16* __restrict__ vd,
    bf16* __restrict__ wqd, bf16* __restrict__ wkd, bf16* __restrict__ wvd,
    bf16* __restrict__ wod,
    bf16* __restrict__ bqd, bf16* __restrict__ bkd,
    bf16* __restrict__ bvd, bf16* __restrict__ bod,
    int* __restrict__ flagsOut)
{
    const int bid = blockIdx.x;
    int id, chunk;
    if (bid < 1536)      { id = bid >> 9;                chunk = bid & 511; }
    else if (bid < 2048) { id = 3 + ((bid - 1536) >> 7); chunk = (bid - 1536) & 127; }
    else                 { id = 7 + (bid - 2048);        chunk = 0; }

    const void* src; bf16* dst; int nelem, nscan;
    switch (id) {
        case 0:  src = q;   dst = qd;  nelem = 1 << 22; nscan = 4096; break;
        case 1:  src = k;   dst = kd;  nelem = 1 << 22; nscan = 4096; break;
        case 2:  src = v;   dst = vd;  nelem = 1 << 22; nscan = 4096; break;
        case 3:  src = wq;  dst = wqd; nelem = 1 << 20; nscan = 4096; break;
        case 4:  src = wk;  dst = wkd; nelem = 1 << 20; nscan = 4096; break;
        case 5:  src = wv;  dst = wvd; nelem = 1 << 20; nscan = 4096; break;
        case 6:  src = wo;  dst = wod; nelem = 1 << 20; nscan = 4096; break;
        case 7:  src = b_q; dst = bqd; nelem = 1024;    nscan = 1024; break;
        case 8:  src = b_k; dst = bkd; nelem = 1024;    nscan = 1024; break;
        case 9:  src = b_v; dst = bvd; nelem = 1024;    nscan = 1024; break;
        default: src = b_o; dst = bod; nelem = 1024;    nscan = 1024; break;
    }

    __shared__ int sbad;
    const int t = threadIdx.x;
    if (t == 0) sbad = 0;
    __syncthreads();
    int loc = scan_f32(src, nscan, t);
    if (loc) atomicOr(&sbad, 1);
    __syncthreads();
    const bool f32 = sbad != 0;

    if (id == 0 && chunk == 0 && t == 0) flagsOut[0] = f32 ? 1 : 0;

    if (id < 7) {
        const int base0 = chunk * 8192 + t * 8;
        if (f32) {
            const float* s = (const float*)src;
#pragma unroll
            for (int r = 0; r < 4; ++r) {
                const int base = base0 + r * 2048;
                const float4 a  = *(const float4*)(s + base);
                const float4 b2 = *(const float4*)(s + base + 4);
                *(bf16x8*)(dst + base) = cvt8(a, b2);
            }
        } else {
            const bf16* s = (const bf16*)src;
#pragma unroll
            for (int r = 0; r < 4; ++r) {
                const int base = base0 + r * 2048;
                *(bf16x8*)(dst + base) = *(const bf16x8*)(s + base);
            }
        }
    } else {
        const int base = t * 8;
        if (base < nelem) {
            if (f32) {
                const float* s = (const float*)src + base;
                const float4 a  = *(const float4*)s;
                const float4 b2 = *(const float4*)(s + 4);
                *(bf16x8*)(dst + base) = cvt8(a, b2);
            } else {
                *(bf16x8*)(dst + base) = *(const bf16x8*)((const bf16*)src + base);
            }
        }
    }
}

// ---------------------------------------------------------------------------
// QKV GEMM, all-bf16 (m97 structure) + XCD-aware tile swizzle (T1): per
// z-slice, flat id f -> swz=(f%8)*32+f/8 (bijective, 256%8==0) so each XCD's
// ~32 consecutive blocks share 4 A-panels (1 MB) and all W-tiles (2 MB) in
// its private L2. C = A @ W^T + bias; z==2 stores V transposed per head.
// ---------------------------------------------------------------------------
__global__ __launch_bounds__(256, 3) void gemm_qkv_kernel(
    const bf16* __restrict__ A0, const bf16* __restrict__ W0,
    const bf16* __restrict__ b0, bf16* __restrict__ C0,
    const bf16* __restrict__ A1, const bf16* __restrict__ W1,
    const bf16* __restrict__ b1, bf16* __restrict__ C1,
    const bf16* __restrict__ A2, const bf16* __restrict__ W2,
    const bf16* __restrict__ b2, bf16* __restrict__ Vtg)
{
    const int z = blockIdx.z;
    const bf16* A  = (z == 0) ? A0 : (z == 1) ? A1 : A2;
    const bf16* W  = (z == 0) ? W0 : (z == 1) ? W1 : W2;
    const bf16* bi = (z == 0) ? b0 : (z == 1) ? b1 : b2;

    __shared__ bf16 As[128 * 32];
    __shared__ bf16 Bs[128 * 32];

    const int t = threadIdx.x;
    const int fid = blockIdx.y * gridDim.x + blockIdx.x;   // 0..255
    const int swz = (fid & 7) * 32 + (fid >> 3);           // XCD-contiguous
    const int n0 = (swz & 7) * 128;
    const int m0 = (swz >> 3) * 128;
    const int w    = t >> 6;
    const int lane = t & 63;
    const int ln   = t & 15;
    const int quad = (t >> 4) & 3;
    const int wm   = (w & 1) * 64;
    const int wn   = (w >> 1) * 64;

    const int srow = w * 32 + (lane >> 2);
    const int scol = (lane & 3) * 8;
    const bf16* gA = A + (size_t)(m0 + srow) * DIM + scol;
    const bf16* gW = W + (size_t)(n0 + srow) * DIM + scol;
    bf16* lA = &As[w * 32 * 32];
    bf16* lW = &Bs[w * 32 * 32];

    f32x4 acc[4][4];
#pragma unroll
    for (int i = 0; i < 4; ++i)
#pragma unroll
        for (int j = 0; j < 4; ++j) acc[i][j] = (f32x4){0.f, 0.f, 0.f, 0.f};

    for (int k0 = 0; k0 < DIM; k0 += 32) {
        __syncthreads();
        glds16(gA + k0,            lA);
        glds16(gA + 16 * DIM + k0, lA + 16 * 32);
        glds16(gW + k0,            lW);
        glds16(gW + 16 * DIM + k0, lW + 16 * 32);
        __syncthreads();

        bf16x8 af[4], bfr[4];
#pragma unroll
        for (int mt = 0; mt < 4; ++mt)
            af[mt] = *(const bf16x8*)&As[(wm + mt * 16 + ln) * 32 + quad * 8];
#pragma unroll
        for (int nt = 0; nt < 4; ++nt)
            bfr[nt] = *(const bf16x8*)&Bs[(wn + nt * 16 + ln) * 32 + quad * 8];
        __builtin_amdgcn_s_setprio(1);
#pragma unroll
        for (int mt = 0; mt < 4; ++mt)
#pragma unroll
            for (int nt = 0; nt < 4; ++nt)
                acc[mt][nt] = MFMA_BF16(af[mt], bfr[nt], acc[mt][nt]);
        __builtin_amdgcn_s_setprio(0);
    }

    if (z == 2) {
        // V epilogue: store transposed per head -> Vt_g[((b*16+h)*64+e)*SEQ + s]
#pragma unroll
        for (int nt = 0; nt < 4; ++nt) {
            const int col = n0 + wn + nt * 16 + ln;       // d
            const int h2 = col >> 6, e = col & 63;
            const float bv = (float)bi[col];
#pragma unroll
            for (int mt = 0; mt < 4; ++mt) {
                const int row = m0 + wm + mt * 16 + quad * 4;
                const int bb = row >> 11, s = row & 2047;
                bf16x4 o = {(bf16)(acc[mt][nt][0] + bv), (bf16)(acc[mt][nt][1] + bv),
                            (bf16)(acc[mt][nt][2] + bv), (bf16)(acc[mt][nt][3] + bv)};
                *(bf16x4*)&Vtg[((size_t)((bb * 16 + h2) * 64 + e)) * SEQ + s] = o;
            }
        }
    } else {
        bf16* C = (z == 0) ? C0 : C1;
#pragma unroll
        for (int nt = 0; nt < 4; ++nt) {
            const int col = n0 + wn + nt * 16 + ln;
            const float bv = (float)bi[col];
#pragma unroll
            for (int mt = 0; mt < 4; ++mt)
#pragma unroll
                for (int r = 0; r < 4; ++r) {
                    const int row = m0 + wm + mt * 16 + quad * 4 + r;
                    C[(size_t)row * DIM + col] = (bf16)(acc[mt][nt][r] + bv);
                }
        }
    }
}

// ---------------------------------------------------------------------------
// Output GEMM (R7 structure) + XCD swizzle: 64x128 tile, 512 blocks = 2/CU.
// ---------------------------------------------------------------------------
__global__ __launch_bounds__(256, 4) void gemm_out_kernel(
    const bf16* __restrict__ A, const bf16* __restrict__ W,
    const bf16* __restrict__ bi, void* __restrict__ C,
    const int* __restrict__ flags)
{
    __shared__ bf16 As[64 * 32];
    __shared__ bf16 Bs[128 * 32];

    const int t = threadIdx.x;
    const bool of32 = flags[0] != 0;

    const int fid = blockIdx.y * gridDim.x + blockIdx.x;   // 0..511
    const int swz = (fid & 7) * 64 + (fid >> 3);           // XCD-contiguous
    const int n0 = (swz & 7) * 128;
    const int m0 = (swz >> 3) * 64;
    const int w    = t >> 6;
    const int lane = t & 63;
    const int ln   = t & 15;
    const int quad = (t >> 4) & 3;
    const int wm   = (w & 1) * 32;
    const int wn   = (w >> 1) * 64;

    const int arow = w * 16 + (lane >> 2);
    const int wrow = w * 32 + (lane >> 2);
    const int scol = (lane & 3) * 8;
    const bf16* gA = A + (size_t)(m0 + arow) * DIM + scol;
    const bf16* gW = W + (size_t)(n0 + wrow) * DIM + scol;
    bf16* lA = &As[(w * 16) * 32];
    bf16* lW = &Bs[(w * 32) * 32];

    f32x4 acc[2][4];
#pragma unroll
    for (int i = 0; i < 2; ++i)
#pragma unroll
        for (int j = 0; j < 4; ++j) acc[i][j] = (f32x4){0.f, 0.f, 0.f, 0.f};

    for (int k0 = 0; k0 < DIM; k0 += 32) {
        __syncthreads();
        glds16(gA + k0,            lA);
        glds16(gW + k0,            lW);
        glds16(gW + 16 * DIM + k0, lW + 16 * 32);
        __syncthreads();

        bf16x8 af[2], bfr[4];
#pragma unroll
        for (int mt = 0; mt < 2; ++mt)
            af[mt] = *(const bf16x8*)&As[(wm + mt * 16 + ln) * 32 + quad * 8];
#pragma unroll
        for (int nt = 0; nt < 4; ++nt)
            bfr[nt] = *(const bf16x8*)&Bs[(wn + nt * 16 + ln) * 32 + quad * 8];
        __builtin_amdgcn_s_setprio(1);
#pragma unroll
        for (int mt = 0; mt < 2; ++mt)
#pragma unroll
            for (int nt = 0; nt < 4; ++nt)
                acc[mt][nt] = MFMA_BF16(af[mt], bfr[nt], acc[mt][nt]);
        __builtin_amdgcn_s_setprio(0);
    }

#pragma unroll
    for (int nt = 0; nt < 4; ++nt) {
        const int col = n0 + wn + nt * 16 + ln;
        const float bv = (float)bi[col];
#pragma unroll
        for (int mt = 0; mt < 2; ++mt)
#pragma unroll
            for (int r = 0; r < 4; ++r) {
                const int row = m0 + wm + mt * 16 + quad * 4 + r;
                if (of32) ((float*)C)[(size_t)row * DIM + col] = acc[mt][nt][r] + bv;
                else      ((bf16*)C)[(size_t)row * DIM + col] = (bf16)(acc[mt][nt][r] + bv);
            }
    }
}

// ---------------------------------------------------------------------------
// Flash attention: R4's proven dbuf body (83.9 us) + three grafts:
//  (1) T1 XCD swizzle: swz=(fid%8)*64+fid/8 (bijective, 512%8==0) -> each
//      XCD's 64 consecutive blocks span 4 bh groups; K/V (512 KB/bh, 2 MB/4)
//      stay L2-resident per XCD instead of re-fetching cross-XCD (FETCH 70MB
//      -> ~30MB predicted).
//  (2) T5 setprio(1) around MFMA clusters: the 2 co-resident blocks drift in
//      phase; prioritize the MFMA-phase wave over the staging-phase wave.
//  (3) defer-max THR=0 (exact): skip rescale when running max didn't grow.
// Double-buffered K/V with counted vmcnt; P through per-wave swizzled LDS.
// LDS = 80 KB -> 2 blocks/CU (grid supplies exactly 2/CU anyway).
// ---------------------------------------------------------------------------
__global__ __launch_bounds__(256, 2) void attn_kernel(
    const bf16* __restrict__ Q, const bf16* __restrict__ K,
    const bf16* __restrict__ Vtg, bf16* __restrict__ O)
{
    const int fid = blockIdx.y * gridDim.x + blockIdx.x;   // 0..511
    const int swz = (fid & 7) * 64 + (fid >> 3);           // XCD-contiguous
    const int qt = swz & 15;          // 0..15: 128 q-rows
    const int bh = swz >> 4;          // 0..31
    const int b  = bh >> 4;
    const int h  = bh & 15;

    __shared__ bf16 Ks[2][128 * 64];  // swizzled, stride 64   (2 x 16 KB)
    __shared__ bf16 Vt[2][64 * 128];  // swizzled, stride 128  (2 x 16 KB)
    __shared__ bf16 Ps[4 * 16 * 128]; // per-wave 16q x 128k, swizzled (16 KB)

    const int t    = threadIdx.x;
    const int w    = t >> 6;
    const int lane = t & 63;
    const int ln   = lane & 15;
    const int quad = lane >> 4;

    const int q0 = qt * 128;

    const float sc = 0.125f * 1.44269504089f;   // 1/sqrt(HD) * log2(e)
    bf16x8 qf[2][2];
#pragma unroll
    for (int g = 0; g < 2; ++g) {
        const bf16* qrow = Q + (size_t)(b * SEQ + q0 + w * 32 + g * 16 + ln) * DIM + h * HDIM;
        qf[g][0] = *(const bf16x8*)(qrow + quad * 8);
        qf[g][1] = *(const bf16x8*)(qrow + 32 + quad * 8);
#pragma unroll
        for (int i = 0; i < 8; ++i) {
            qf[g][0][i] = (bf16)((float)qf[g][0][i] * sc);
            qf[g][1][i] = (bf16)((float)qf[g][1][i] * sc);
        }
    }

    f32x4 o_acc[2][4];
#pragma unroll
    for (int g = 0; g < 2; ++g)
#pragma unroll
        for (int c = 0; c < 4; ++c) o_acc[g][c] = (f32x4){0.f, 0.f, 0.f, 0.f};
    float m_s[2] = {-1e30f, -1e30f};
    float l_s[2] = {0.f, 0.f};

    // K staging: wave w, instr i stages rows w*32+i*8 .. +7 (8 rows x 8 chunks)
    const int kr_off = lane >> 3;               // row-in-group 0..7
    const int k_lc   = (lane & 7) ^ kr_off;     // logical chunk (source swizzle)
    // V staging: wave w, instr i stages e-rows w*16+i*4 .. +3 (4 rows x 16 chunks)
    const int ve_off = lane >> 4;               // 0..3
    const int v_pc   = lane & 15;               // phys chunk
    const size_t vrowbase = (size_t)((b * 16 + h) * 64);

    const int psbase = (w * 16 + ln) * 128;     // per-wave row, stride 128
    const int pmask  = (ln & 15) << 1;          // 8B-slot XOR swizzle (even)

#define STAGE_KV(BUF, KB)                                                     \
    {                                                                         \
        _Pragma("unroll")                                                     \
        for (int i = 0; i < 4; ++i) {                                         \
            const int r = w * 32 + i * 8 + kr_off;                            \
            glds16(K + (size_t)(b * SEQ + (KB) + r) * DIM + h * HDIM + k_lc * 8, \
                   &Ks[BUF][(w * 32 + i * 8) * 64]);                          \
        }                                                                     \
        _Pragma("unroll")                                                     \
        for (int i = 0; i < 4; ++i) {                                         \
            const int e2 = w * 16 + i * 4 + ve_off;                           \
            const int lc = v_pc ^ (i * 4 + ve_off);                           \
            glds16(Vtg + (vrowbase + e2) * SEQ + (KB) + lc * 8,               \
                   &Vt[BUF][(w * 16 + i * 4) * 128]);                         \
        }                                                                     \
    }

    STAGE_KV(0, 0);                    // prologue: tile 0 in flight

    for (int it = 0; it < SEQ / 128; ++it) {
        const int cur = it & 1;
        if (it < SEQ / 128 - 1) {
            STAGE_KV(cur ^ 1, (it + 1) * 128);          // prefetch tile t+1
            __asm__ volatile("s_waitcnt vmcnt(8)" ::: "memory");  // t done, t+1 in flight
        } else {
            __asm__ volatile("s_waitcnt vmcnt(0)" ::: "memory");
        }
        __builtin_amdgcn_sched_barrier(0);
        __builtin_amdgcn_s_barrier();   // all waves' tile-t portions visible
        __builtin_amdgcn_sched_barrier(0);

        // ---- S^T = K·Q^T for both q-groups; K-frags loaded once
        f32x4 sa0[8], sa1[8];
        __builtin_amdgcn_s_setprio(1);
#pragma unroll
        for (int nt = 0; nt < 8; ++nt) {
            const int rr = (nt * 16 + ln) * 64;
            const bf16x8 kf0 = *(const bf16x8*)&Ks[cur][rr + ((quad ^ (ln & 7)) << 3)];
            const bf16x8 kf1 = *(const bf16x8*)&Ks[cur][rr + (((quad + 4) ^ (ln & 7)) << 3)];
            f32x4 z0 = (f32x4){0.f, 0.f, 0.f, 0.f};
            z0 = MFMA_BF16(kf0, qf[0][0], z0);
            z0 = MFMA_BF16(kf1, qf[0][1], z0);
            sa0[nt] = z0;
            f32x4 z1 = (f32x4){0.f, 0.f, 0.f, 0.f};
            z1 = MFMA_BF16(kf0, qf[1][0], z1);
            z1 = MFMA_BF16(kf1, qf[1][1], z1);
            sa1[nt] = z1;
        }
        __builtin_amdgcn_s_setprio(0);

        // ---- online softmax with defer-max THR=0 (exact skip)
#pragma unroll
        for (int g = 0; g < 2; ++g) {
            f32x4* sa = g ? sa1 : sa0;
            float m8[8];
#pragma unroll
            for (int nt = 0; nt < 8; ++nt)
                m8[nt] = fmaxf(fmaxf(sa[nt][0], sa[nt][1]), fmaxf(sa[nt][2], sa[nt][3]));
            float mx = fmaxf(fmaxf(fmaxf(m8[0], m8[1]), fmaxf(m8[2], m8[3])),
                             fmaxf(fmaxf(m8[4], m8[5]), fmaxf(m8[6], m8[7])));
            mx = fmaxf(mx, __shfl_xor(mx, 16));
            mx = fmaxf(mx, __shfl_xor(mx, 32));
            if (!__all(mx <= m_s[g])) {
                const float mn = fmaxf(m_s[g], mx);
                const float al = exp2f(m_s[g] - mn);
                m_s[g] = mn;
                l_s[g] *= al;
#pragma unroll
                for (int r = 0; r < 4; ++r) {
                    const float alr = __shfl(al, quad * 4 + r);
#pragma unroll
                    for (int c = 0; c < 4; ++c) o_acc[g][c][r] *= alr;
                }
            }
            const float mn = m_s[g];
            float r8[8];
#pragma unroll
            for (int nt = 0; nt < 8; ++nt) {
                float p0 = exp2f(sa[nt][0] - mn);
                float p1 = exp2f(sa[nt][1] - mn);
                float p2 = exp2f(sa[nt][2] - mn);
                float p3 = exp2f(sa[nt][3] - mn);
                sa[nt][0] = p0; sa[nt][1] = p1; sa[nt][2] = p2; sa[nt][3] = p3;
                r8[nt] = (p0 + p1) + (p2 + p3);
            }
            float rs = ((r8[0] + r8[1]) + (r8[2] + r8[3])) +
                       ((r8[4] + r8[5]) + (r8[6] + r8[7]));
            rs += __shfl_xor(rs, 16);
            rs += __shfl_xor(rs, 32);
            l_s[g] += rs;
        }

        // ---- P g0 -> Ps (per-wave rows, swizzled slots)
#pragma unroll
        for (int nt = 0; nt < 8; ++nt) {
            bf16x4 pk = {(bf16)sa0[nt][0], (bf16)sa0[nt][1],
                         (bf16)sa0[nt][2], (bf16)sa0[nt][3]};
            *(bf16x4*)&Ps[psbase + (((nt * 4 + quad) ^ pmask) << 2)] = pk;
        }
        __asm__ volatile("s_waitcnt lgkmcnt(0)" ::: "memory");
        bf16x8 pf0[4];
#pragma unroll
        for (int kc = 0; kc < 4; ++kc)
            pf0[kc] = *(const bf16x8*)&Ps[psbase + (((kc * 8 + quad * 2) ^ pmask) << 2)];
        __asm__ volatile("s_waitcnt lgkmcnt(0)" ::: "memory");
        // ---- P g1 -> Ps (same rows; overlaps g0 MFMAs below)
#pragma unroll
        for (int nt = 0; nt < 8; ++nt) {
            bf16x4 pk = {(bf16)sa1[nt][0], (bf16)sa1[nt][1],
                         (bf16)sa1[nt][2], (bf16)sa1[nt][3]};
            *(bf16x4*)&Ps[psbase + (((nt * 4 + quad) ^ pmask) << 2)] = pk;
        }
        // ---- V frags (swizzled), loaded once for both groups
        bf16x8 vf[4][4];
#pragma unroll
        for (int kc = 0; kc < 4; ++kc)
#pragma unroll
            for (int c = 0; c < 4; ++c) {
                const int e = c * 16 + ln;
                const int pc = (kc * 4 + quad) ^ ln;
                vf[kc][c] = *(const bf16x8*)&Vt[cur][e * 128 + pc * 8];
            }
        __asm__ volatile("s_waitcnt lgkmcnt(0)" ::: "memory");

        __builtin_amdgcn_s_setprio(1);
#pragma unroll
        for (int kc = 0; kc < 4; ++kc)
#pragma unroll
            for (int c = 0; c < 4; ++c)
                o_acc[0][c] = MFMA_BF16(pf0[kc], vf[kc][c], o_acc[0][c]);
        __builtin_amdgcn_s_setprio(0);
        bf16x8 pf1[4];
#pragma unroll
        for (int kc = 0; kc < 4; ++kc)
            pf1[kc] = *(const bf16x8*)&Ps[psbase + (((kc * 8 + quad * 2) ^ pmask) << 2)];
        __asm__ volatile("s_waitcnt lgkmcnt(0)" ::: "memory");
        __builtin_amdgcn_s_setprio(1);
#pragma unroll
        for (int kc = 0; kc < 4; ++kc)
#pragma unroll
            for (int c = 0; c < 4; ++c)
                o_acc[1][c] = MFMA_BF16(pf1[kc], vf[kc][c], o_acc[1][c]);
        __builtin_amdgcn_s_setprio(0);

        __builtin_amdgcn_sched_barrier(0);
        __builtin_amdgcn_s_barrier();   // all waves done reading tile t
    }
#undef STAGE_KV

    // ---- epilogue: normalize, store bf16
#pragma unroll
    for (int g = 0; g < 2; ++g) {
        const float linv = 1.0f / l_s[g];
#pragma unroll
        for (int r = 0; r < 4; ++r) {
            const float lr = __shfl(linv, quad * 4 + r);
            const size_t rowoff =
                (size_t)(b * SEQ + q0 + w * 32 + g * 16 + quad * 4 + r) * DIM + h * HDIM;
#pragma unroll
            for (int c = 0; c < 4; ++c)
                O[rowoff + c * 16 + ln] = (bf16)(o_acc[g][c][r] * lr);
        }
    }
}

extern "C" void kernel_launch(void* const* d_in, const int* in_sizes, int n_in,
                              void* d_out, int out_size, void* d_ws, size_t ws_size,
                              hipStream_t stream) {
    // ws layout (bf16 elems): Qb,Kb,Vtg (4.19M each), qc,kc,vc (4.19M each;
    // qc is re-used as Ob after gemm_qkv has consumed it), Wq..Wo (1.05M
    // each), biases (1K each), flags. Total ~59 MB.
    const size_t NM = (size_t)MROWS * DIM;     // 4194304
    const size_t NW = (size_t)DIM * DIM;       // 1048576
    bf16* Qb  = (bf16*)d_ws;
    bf16* Kb  = Qb + NM;
    bf16* Vtg = Kb + NM;
    bf16* qc  = Vtg + NM;
    bf16* kc  = qc + NM;
    bf16* vc  = kc + NM;
    bf16* Wqc = vc + NM;
    bf16* Wkc = Wqc + NW;
    bf16* Wvc = Wkc + NW;
    bf16* Woc = Wvc + NW;
    bf16* bqc = Woc + NW;
    bf16* bkc = bqc + 1024;
    bf16* bvc = bkc + 1024;
    bf16* boc = bvc + 1024;
    int*  flags = (int*)(boc + 1024);
    bf16* Ob  = qc;   // alias: qc dead after gemm_qkv, Ob written by attn

    convert_kernel<<<dim3(2052), 256, 0, stream>>>(
        d_in[0], d_in[1], d_in[2],
        d_in[3], d_in[5], d_in[7], d_in[9],
        d_in[4], d_in[6], d_in[8], d_in[10],
        qc, kc, vc, Wqc, Wkc, Wvc, Woc, bqc, bkc, bvc, boc, flags);

    gemm_qkv_kernel<<<dim3(DIM / 128, MROWS / 128, 3), 256, 0, stream>>>(
        qc, Wqc, bqc, Qb,
        kc, Wkc, bkc, Kb,
        vc, Wvc, bvc, Vtg);

    attn_kernel<<<dim3(SEQ / 128, BATCH * 16), 256, 0, stream>>>(Qb, Kb, Vtg, Ob);

    gemm_out_kernel<<<dim3(DIM / 128, MROWS / 64), 256, 0, stream>>>(
        Ob, Woc, boc, d_out, flags);
}